// Round 13
// baseline (194.773 us; speedup 1.0000x reference)
//
#include <hip/hip_runtime.h>

// MultiHeadAttention: B=2, S=2048, D=1024, H=16, hd=64. fp32 I/O.
// Round 29: (1) gemm256_qkv gets a ROLLING subtile pipeline: stage
// subtile s+1 into buf^1 while computing subtile s from buf, ONE barrier
// per 32-wide subtile. LDS stays 32KB -> 3 blocks/CU preserved (R25's
// mistake was doubling LDS for the pipeline; this rolls within the
// existing two buffers). Math bit-identical (K-order unchanged).
// (2) wo64 reverted to R26/R10-exact 64x128 BK=128 (64x64 experiment was
// neutral). attn_v16 unchanged (best passing). qkv 2D XCD chunk + direct
// transposed V epilogue kept.

typedef __attribute__((ext_vector_type(8))) short short8;
typedef __attribute__((ext_vector_type(4))) short short4v;
typedef __attribute__((ext_vector_type(4))) float floatx4;

__device__ inline unsigned short f2bf(float f) {
  unsigned u = __float_as_uint(f);
  unsigned r = (u + 0x7fffu + ((u >> 16) & 1u)) >> 16;  // RNE
  return (unsigned short)r;
}

__device__ __forceinline__ float fast_exp2(float x) {
#if __has_builtin(__builtin_amdgcn_exp2f)
  return __builtin_amdgcn_exp2f(x);
#else
  float r;
  asm volatile("v_exp_f32_e32 %0, %1" : "=v"(r) : "v"(x));
  return r;
#endif
}

__device__ __forceinline__ void gll16(const unsigned short* g, unsigned short* l) {
  __builtin_amdgcn_global_load_lds(
      (const __attribute__((address_space(1))) unsigned int*)(g),
      (__attribute__((address_space(3))) unsigned int*)(l),
      16, 0, 0);
}

constexpr int B_ = 2, S_ = 2048, D_ = 1024, H_ = 16, HD_ = 64;

// ---------------------------------------------------------------------------
// Merged one-time converter: z=0..3 -> W transpose+convert; z=4 -> X convert.
// ---------------------------------------------------------------------------
__global__ __launch_bounds__(256) void prep_inputs(
    const float* __restrict__ x, unsigned short* __restrict__ xb,
    const float* __restrict__ w0, const float* __restrict__ w1,
    const float* __restrict__ w2, const float* __restrict__ w3,
    unsigned short* __restrict__ wt_base)
{
  if (blockIdx.z == 4) {
    const int tid = threadIdx.y * 32 + threadIdx.x;
    const size_t base =
        ((size_t)(blockIdx.y * 32 + blockIdx.x) * 256 + tid) * 16;
#pragma unroll
    for (int half = 0; half < 2; ++half) {
      const size_t i = base + half * 8;
      float4 a = *(const float4*)(x + i);
      float4 b = *(const float4*)(x + i + 4);
      short8 o;
      o[0] = (short)f2bf(a.x); o[1] = (short)f2bf(a.y);
      o[2] = (short)f2bf(a.z); o[3] = (short)f2bf(a.w);
      o[4] = (short)f2bf(b.x); o[5] = (short)f2bf(b.y);
      o[6] = (short)f2bf(b.z); o[7] = (short)f2bf(b.w);
      *(short8*)(xb + i) = o;
    }
    return;
  }
  const float* src;
  switch (blockIdx.z) {
    case 0: src = w0; break;
    case 1: src = w1; break;
    case 2: src = w2; break;
    default: src = w3; break;
  }
  unsigned short* dst = wt_base + (size_t)blockIdx.z * 1024 * 1024;
  __shared__ unsigned short t[32][33];
  const int bx = blockIdx.x * 32;  // n
  const int by = blockIdx.y * 32;  // k
  const int x_ = threadIdx.x;
  for (int yy = threadIdx.y; yy < 32; yy += 8)
    t[yy][x_] = f2bf(src[(size_t)(by + yy) * 1024 + bx + x_]);
  __syncthreads();
  for (int yy = threadIdx.y; yy < 32; yy += 8)
    dst[(size_t)(bx + yy) * 1024 + by + x_] = t[x_][yy];
}

// ---------------------------------------------------------------------------
// QKV GEMM: 128x128 tile, ROLLING 32-wide subtile pipeline (stage s+1 into
// buf^1 || compute s; one barrier/subtile; LDS 32KB, 3 blocks/CU) +
// 2D XCD chunk. V-projection blocks write transposed into Vt[(bh*64+d)][s].
// ---------------------------------------------------------------------------
__global__ __launch_bounds__(256) void gemm256_qkv(
    const unsigned short* __restrict__ A,
    const unsigned short* __restrict__ Bt,
    unsigned short* __restrict__ Qo,
    unsigned short* __restrict__ Ko,
    unsigned short* __restrict__ Vt)
{
  __shared__ unsigned short sA[2][128 * 32];
  __shared__ unsigned short sB[2][128 * 32];
  const int K = 1024;
  const int NSUB = K / 32;  // 32 subtiles

  // 2D XCD chunk (bijective): xcd = L&7 owns rows [(xcd>>1)*8,+8) x
  // cols [(xcd&1)*12,+12), walked row-major: 12 B-panels (3MB) resident.
  const int L = blockIdx.y * 24 + blockIdx.x;
  const int xcd = L & 7, i = L >> 3;
  const int brow = (xcd >> 1) * 8 + i / 12;
  const int bcol = (xcd & 1) * 12 + i % 12;
  const int m0 = brow * 128;
  const int bn0 = bcol * 128;

  const int tid = threadIdx.x, wave = tid >> 6, lane = tid & 63;
  const int g = lane >> 4, ml = lane & 15;
  const int wm = wave & 1, wn = wave >> 1;

  const unsigned short* ag0 = A + (size_t)(m0 + (tid >> 2)) * K + (tid & 3) * 8;
  const unsigned short* ag1 = ag0 + (size_t)64 * K;
  const unsigned short* bg0 = Bt + (size_t)(bn0 + (tid >> 2)) * K + (tid & 3) * 8;
  const unsigned short* bg1 = bg0 + (size_t)64 * K;
  const int woff = wave * 512;

  floatx4 acc[4][4];
#pragma unroll
  for (int mt = 0; mt < 4; ++mt)
#pragma unroll
    for (int nt = 0; nt < 4; ++nt) acc[mt][nt] = (floatx4){0.f, 0.f, 0.f, 0.f};

  // prologue: stage subtile 0 into buf 0 (one unhidden drain)
  gll16(ag0, sA[0] + woff);
  gll16(ag1, sA[0] + 2048 + woff);
  gll16(bg0, sB[0] + woff);
  gll16(bg1, sB[0] + 2048 + woff);
  __syncthreads();

  for (int s = 0; s < NSUB; ++s) {
    const int buf = s & 1;
    // stage NEXT subtile into buf^1 (drained at end-of-iter barrier,
    // hidden under this iteration's compute). buf^1's readers finished
    // at the previous barrier.
    if (s + 1 < NSUB) {
      const int ko = (s + 1) * 32;
      gll16(ag0 + ko, sA[buf ^ 1] + woff);
      gll16(ag1 + ko, sA[buf ^ 1] + 2048 + woff);
      gll16(bg0 + ko, sB[buf ^ 1] + woff);
      gll16(bg1 + ko, sB[buf ^ 1] + 2048 + woff);
    }
    // compute current subtile
    short8 af[4], bf[4];
#pragma unroll
    for (int mt = 0; mt < 4; ++mt)
      af[mt] = *(const short8*)(sA[buf] + (wm * 64 + mt * 16 + ml) * 32 + g * 8);
#pragma unroll
    for (int nt = 0; nt < 4; ++nt)
      bf[nt] = *(const short8*)(sB[buf] + (wn * 64 + nt * 16 + ml) * 32 + g * 8);
#pragma unroll
    for (int mt = 0; mt < 4; ++mt)
#pragma unroll
      for (int nt = 0; nt < 4; ++nt)
        acc[mt][nt] = __builtin_amdgcn_mfma_f32_16x16x32_bf16(
            af[mt], bf[nt], acc[mt][nt], 0, 0, 0);
    __syncthreads();
  }

  const int proj = bcol >> 3;
  const int col0 = (bcol & 7) * 128;
  if (proj < 2) {
    unsigned short* out = (proj == 0) ? Qo : Ko;
#pragma unroll
    for (int mt = 0; mt < 4; ++mt) {
#pragma unroll
      for (int nt = 0; nt < 4; ++nt) {
        const int col = col0 + wn * 64 + nt * 16 + ml;
#pragma unroll
        for (int r = 0; r < 4; ++r) {
          const int row = m0 + wm * 64 + mt * 16 + g * 4 + r;
          out[(size_t)row * 1024 + col] = f2bf(acc[mt][nt][r]);
        }
      }
    }
  } else {
    // V: write transposed: Vt[((b*16+h)*64+d)*2048 + s], 4 consecutive s
    // (r=0..3) packed into one 8B store. b constant per block (128 | 2048).
    const int bq = m0 >> 11;
    const int sbase = (m0 & 2047);
#pragma unroll
    for (int mt = 0; mt < 4; ++mt) {
      const int s0 = sbase + wm * 64 + mt * 16 + g * 4;
#pragma unroll
      for (int nt = 0; nt < 4; ++nt) {
        const int col = col0 + wn * 64 + nt * 16 + ml;  // V column 0..1023
        const int h = col >> 6, d = col & 63;
        short4v o;
        o[0] = (short)f2bf(acc[mt][nt][0]);
        o[1] = (short)f2bf(acc[mt][nt][1]);
        o[2] = (short)f2bf(acc[mt][nt][2]);
        o[3] = (short)f2bf(acc[mt][nt][3]);
        *(short4v*)(Vt + ((size_t)((bq * 16 + h) * 64 + d)) * 2048 + s0) = o;
      }
    }
  }
}

// Output projection, 64x128 tile, BK=128 four-subtile staging + XCD swizzle
// (R26-exact structure).
__global__ __launch_bounds__(256) void gemm_wo64(
    const unsigned short* __restrict__ A,
    const unsigned short* __restrict__ Bt,
    const float* __restrict__ bias,
    float* __restrict__ C)
{
  __shared__ unsigned short sA[4][64 * 32];
  __shared__ unsigned short sB[4][128 * 32];
  const int K = 1024;

  // XCD swizzle (bijective: 512 % 8 == 0): 8 row-panels x 8 cols per XCD.
  const int L = blockIdx.y * 8 + blockIdx.x;
  const int rid = (L & 7) * 64 + (L >> 3);
  const int m0 = (rid >> 3) * 64;
  const int bn0 = (rid & 7) * 128;

  const int tid = threadIdx.x, wave = tid >> 6, lane = tid & 63;
  const int g = lane >> 4, ml = lane & 15;
  const int wm = wave & 1, wn = wave >> 1;

  const unsigned short* ag =
      A + (size_t)(m0 + wave * 16 + (lane >> 2)) * K + (lane & 3) * 8;
  const unsigned short* bg0 = Bt + (size_t)(bn0 + (tid >> 2)) * K + (tid & 3) * 8;
  const unsigned short* bg1 = bg0 + (size_t)64 * K;
  const int woff = wave * 512;

  floatx4 acc[2][4];
#pragma unroll
  for (int mt = 0; mt < 2; ++mt)
#pragma unroll
    for (int nt = 0; nt < 4; ++nt) acc[mt][nt] = (floatx4){0.f, 0.f, 0.f, 0.f};

  for (int k0 = 0; k0 < K; k0 += 128) {
    __syncthreads();
#pragma unroll
    for (int t = 0; t < 4; ++t) {
      gll16(ag + k0 + t * 32, sA[t] + woff);
      gll16(bg0 + k0 + t * 32, sB[t] + woff);
      gll16(bg1 + k0 + t * 32, sB[t] + 2048 + woff);
    }
    __syncthreads();
#pragma unroll
    for (int t = 0; t < 4; ++t) {
      short8 af[2], bf[4];
#pragma unroll
      for (int mt = 0; mt < 2; ++mt)
        af[mt] = *(const short8*)(sA[t] + (wm * 32 + mt * 16 + ml) * 32 + g * 8);
#pragma unroll
      for (int nt = 0; nt < 4; ++nt)
        bf[nt] = *(const short8*)(sB[t] + (wn * 64 + nt * 16 + ml) * 32 + g * 8);
#pragma unroll
      for (int mt = 0; mt < 2; ++mt)
#pragma unroll
        for (int nt = 0; nt < 4; ++nt)
          acc[mt][nt] = __builtin_amdgcn_mfma_f32_16x16x32_bf16(
              af[mt], bf[nt], acc[mt][nt], 0, 0, 0);
    }
  }

#pragma unroll
  for (int mt = 0; mt < 2; ++mt) {
#pragma unroll
    for (int nt = 0; nt < 4; ++nt) {
      const int col = bn0 + wn * 64 + nt * 16 + ml;
      const float badd = bias[col];
#pragma unroll
      for (int r = 0; r < 4; ++r) {
        const int row = m0 + wm * 32 + mt * 16 + g * 4 + r;
        C[(size_t)row * 1024 + col] = acc[mt][nt][r] + badd;
      }
    }
  }
}

// ---------------------------------------------------------------------------
// Attention v16 (unchanged, best passing): 8-wave parity split, fused A/B
// dual-tile, K+V LDS staging, 2-phase pipeline, in-register softmax,
// raw-f32 l partials, setprio around MFMA clusters. Runtime diag bools.
// LDS: 2 bufs x 2 tiles x (K 8KB + V 8KB) = 64KB; union comb 36KB.
// ---------------------------------------------------------------------------
constexpr int KTPB = 2;  // k-tiles per buffer group

struct AttnLds {
  unsigned short k0[2][KTPB][64 * 32];
  unsigned short k1[2][KTPB][64 * 32];
  unsigned short v0[2][KTPB][64 * 32];
  unsigned short v1[2][KTPB][64 * 32];
};
union __align__(16) AttnLdsU {
  AttnLds t;
  float comb[4 * 64 * 36];  // 36 KB <= 64 KB; used after last barrier
};

// softmax + pack + permlane redistribute: s -> ap[2] (PV A-frags).
// l sums RAW f32 (4 partials); v_perm byte-select truncates P to bf16.
__device__ __forceinline__ void softmax_pack(
    const floatx4* s, const bool diag, const int qg, const int kb,
    float& l, short8* ap)
{
  const float C1 = 0.18033688f;    // 0.125 / ln2
  const float C2 = -34.6246810f;   // -24 / ln2

  unsigned wb[4][4];
  float lp0 = 0.f, lp1 = 0.f, lp2 = 0.f, lp3 = 0.f;
#pragma unroll
  for (int nb = 0; nb < 4; ++nb) {
#pragma unroll
    for (int r = 0; r < 4; ++r) {
      float wv = fast_exp2(fmaf(s[nb][r], C1, C2));
      if (diag && (kb + nb * 16 + r > qg)) wv = 0.f;
      wb[nb][r] = __float_as_uint(wv);
      if (nb == 0) lp0 += wv;
      else if (nb == 1) lp1 += wv;
      else if (nb == 2) lp2 += wv;
      else lp3 += wv;
    }
  }
  l += (lp0 + lp1) + (lp2 + lp3);

  // pack pairs along r (v_perm bytes 2,3 of each source = truncated bf16)
  unsigned pk[4][2];
#pragma unroll
  for (int nb = 0; nb < 4; ++nb) {
    pk[nb][0] = __builtin_amdgcn_perm(wb[nb][1], wb[nb][0], 0x07060302u);
    pk[nb][1] = __builtin_amdgcn_perm(wb[nb][3], wb[nb][2], 0x07060302u);
  }

  // redistribute to PV A-frag: 2x permlane32_swap + 2x permlane16_swap per rr
  unsigned Fr[2][4];
#pragma unroll
  for (int rr = 0; rr < 2; ++rr) {
    unsigned a0 = pk[0][rr], a1 = pk[1][rr];
    unsigned a2 = pk[2][rr], a3 = pk[3][rr];
    asm("v_permlane32_swap_b32 %0, %1" : "+v"(a0), "+v"(a1));
    asm("v_permlane32_swap_b32 %0, %1" : "+v"(a2), "+v"(a3));
    asm("v_permlane16_swap_b32 %0, %1" : "+v"(a0), "+v"(a1));
    asm("v_permlane16_swap_b32 %0, %1" : "+v"(a2), "+v"(a3));
    Fr[0][rr] = a0; Fr[0][2 + rr] = a1;
    Fr[1][rr] = a2; Fr[1][2 + rr] = a3;
  }
#pragma unroll
  for (int f = 0; f < 2; ++f) {
    union { unsigned u[4]; short8 s8; } uap;
    uap.u[0] = Fr[f][0]; uap.u[1] = Fr[f][1];
    uap.u[2] = Fr[f][2]; uap.u[3] = Fr[f][3];
    ap[f] = uap.s8;
  }
}

// Fused dual-q-block tile: K/V fragments read ONCE, feed both MFMA chains.
template <bool DUAL>
__device__ __forceinline__ void attn_tile2(
    const short8* aqB, const short8* aqA,
    const unsigned short* sK0, const unsigned short* sK1,
    const unsigned short* sV0, const unsigned short* sV1,
    floatx4* accB, float& lB, floatx4* accA, float& lA,
    const bool diagB, const bool diagA,
    const int qgB, const int qgA, const int kb,
    const int g, const int ml)
{
  floatx4 sB[4], sA[4];
  __builtin_amdgcn_s_setprio(1);
#pragma unroll
  for (int nb = 0; nb < 4; ++nb) {
    short8 bk0 = *(const short8*)(sK0 + (nb * 16 + ml) * 32 + g * 8);
    short8 bk1 = *(const short8*)(sK1 + (nb * 16 + ml) * 32 + g * 8);
    sB[nb] = (floatx4){0.f, 0.f, 0.f, 0.f};
    sB[nb] = __builtin_amdgcn_mfma_f32_16x16x32_bf16(bk0, aqB[0], sB[nb], 0, 0, 0);
    sB[nb] = __builtin_amdgcn_mfma_f32_16x16x32_bf16(bk1, aqB[1], sB[nb], 0, 0, 0);
    if (DUAL) {
      sA[nb] = (floatx4){0.f, 0.f, 0.f, 0.f};
      sA[nb] = __builtin_amdgcn_mfma_f32_16x16x32_bf16(bk0, aqA[0], sA[nb], 0, 0, 0);
      sA[nb] = __builtin_amdgcn_mfma_f32_16x16x32_bf16(bk1, aqA[1], sA[nb], 0, 0, 0);
    }
  }
  __builtin_amdgcn_s_setprio(0);

  short8 apB[2], apA[2];
  softmax_pack(sB, diagB, qgB, kb, lB, apB);
  if (DUAL) softmax_pack(sA, diagA, qgA, kb, lA, apA);

  __builtin_amdgcn_s_setprio(1);
#pragma unroll
  for (int f = 0; f < 2; ++f) {
    const unsigned short* sv = f ? sV1 : sV0;
#pragma unroll
    for (int jd = 0; jd < 4; ++jd) {
      short8 bv = *(const short8*)(sv + (jd * 16 + ml) * 32 + g * 8);
      accB[jd] = __builtin_amdgcn_mfma_f32_16x16x32_bf16(apB[f], bv, accB[jd], 0, 0, 0);
      if (DUAL)
        accA[jd] = __builtin_amdgcn_mfma_f32_16x16x32_bf16(apA[f], bv, accA[jd], 0, 0, 0);
    }
  }
  __builtin_amdgcn_s_setprio(0);
}

__global__ __launch_bounds__(512) void attn_v16(
    const unsigned short* __restrict__ Q,
    const unsigned short* __restrict__ Kg,
    const unsigned short* __restrict__ Vt,
    unsigned short* __restrict__ CTX)
{
  __shared__ AttnLdsU lds;

  // XCD-chunked swizzle (bijective: 512 % 8 == 0): groups 4 consecutive bh
  // per XCD -> K/V working set 2MB < 4MB L2.
  const int L = blockIdx.x;
  const int rid = (L & 7) * 64 + (L >> 3);
  const int p = rid & 15;
  const int bh = rid >> 4;

  const int b = bh >> 4, h = bh & 15;
  const int qbA = p, qbB = 31 - p;
  const int qA0 = qbA * 64, qB0 = qbB * 64;
  const int tid = threadIdx.x, w = tid >> 6, lane = tid & 63;
  const int slice = w & 3, par = w >> 2;
  const int g = lane >> 4, ml = lane & 15;

  const size_t headoff = (size_t)b * S_ * D_ + (size_t)h * HD_;
  const size_t vtoff   = (size_t)bh * HD_ * S_;

  short8 aqA[2], aqB[2];
  {
    const unsigned short* qp =
        Q + headoff + (size_t)(qA0 + slice * 16 + ml) * D_ + g * 8;
    aqA[0] = *(const short8*)qp;
    aqA[1] = *(const short8*)(qp + 32);
  }
  {
    const unsigned short* qp =
        Q + headoff + (size_t)(qB0 + slice * 16 + ml) * D_ + g * 8;
    aqB[0] = *(const short8*)qp;
    aqB[1] = *(const short8*)(qp + 32);
  }

  floatx4 accA[4], accB[4];
#pragma unroll
  for (int jd = 0; jd < 4; ++jd) {
    accA[jd] = (floatx4){0.f, 0.f, 0.f, 0.f};
    accB[jd] = (floatx4){0.f, 0.f, 0.f, 0.f};
  }
  float lA = 0.f, lB = 0.f;
  const int qgA = qA0 + slice * 16 + ml;   // this lane's q-row (A block)
  const int qgB = qB0 + slice * 16 + ml;

  // staging: waves 0-3 handle K, waves 4-7 handle V; each covers 16 rows.
  const int sw = slice;
  const unsigned short* kgb =
      Kg + headoff + (size_t)(sw * 16 + (lane >> 2)) * D_ + (lane & 3) * 8;
  const unsigned short* vgb =
      Vt + vtoff + (size_t)(sw * 16 + (lane >> 2)) * S_ + (lane & 3) * 8;
  const int woff = sw * 512;

  const int ntiles = qbB + 1;

  // ---- stage group 0 into buf 0 (prologue; one unhidden drain) ----
  {
    const int cnt = (ntiles < KTPB) ? ntiles : KTPB;
#pragma unroll
    for (int t = 0; t < KTPB; ++t) {
      if (t >= cnt) break;
      if (w < 4) {
        const size_t ko = (size_t)t * 64 * D_;
        gll16(kgb + ko,      lds.t.k0[0][t] + woff);
        gll16(kgb + ko + 32, lds.t.k1[0][t] + woff);
      } else {
        gll16(vgb + t * 64,      lds.t.v0[0][t] + woff);
        gll16(vgb + t * 64 + 32, lds.t.v1[0][t] + woff);
      }
    }
  }
  __syncthreads();

  for (int kt0 = 0; kt0 < ntiles; kt0 += KTPB) {
    const int bufi = (kt0 >> 1) & 1;
    // ---- stage NEXT group into buf^1 (issue early; drained at barrier) ----
    const int nxt = kt0 + KTPB;
    if (nxt < ntiles) {
      const int cn = (ntiles - nxt < KTPB) ? (ntiles - nxt) : KTPB;
#pragma unroll
      for (int t = 0; t < KTPB; ++t) {
        if (t >= cn) break;
        const int kt = nxt + t;
        if (w < 4) {
          const size_t ko = (size_t)kt * 64 * D_;
          gll16(kgb + ko,      lds.t.k0[bufi ^ 1][t] + woff);
          gll16(kgb + ko + 32, lds.t.k1[bufi ^ 1][t] + woff);
        } else {
          gll16(vgb + kt * 64,      lds.t.v0[bufi ^ 1][t] + woff);
          gll16(vgb + kt * 64 + 32, lds.t.v1[bufi ^ 1][t] + woff);
        }
      }
    }

    // ---- compute current buf (A/B fused when both in causal range) ----
    const int cnt = (ntiles - kt0 < KTPB) ? (ntiles - kt0) : KTPB;  // uniform
    if (par < cnt) {
      const int kt = kt0 + par;
      const int kb = kt * 64 + g * 4;
      if (kt <= qbA)
        attn_tile2<true>(aqB, aqA,
                         lds.t.k0[bufi][par], lds.t.k1[bufi][par],
                         lds.t.v0[bufi][par], lds.t.v1[bufi][par],
                         accB, lB, accA, lA,
                         kt == qbB, kt == qbA, qgB, qgA, kb, g, ml);
      else
        attn_tile2<false>(aqB, aqA,
                          lds.t.k0[bufi][par], lds.t.k1[bufi][par],
                          lds.t.v0[bufi][par], lds.t.v1[bufi][par],
                          accB, lB, accA, lA,
                          kt == qbB, false, qgB, qgA, kb, g, ml);
    }
    __syncthreads();  // drains next-group loads (hidden under compute)
  }

  // ---- combine parity pairs (w, w+4) through LDS ----
  {
    float* slot = lds.comb + (size_t)(slice * 64 + lane) * 36;
    if (par == 1) {
#pragma unroll
      for (int jd = 0; jd < 4; ++jd) {
        *(floatx4*)(slot + jd * 4) = accA[jd];
        *(floatx4*)(slot + 16 + jd * 4) = accB[jd];
      }
      slot[32] = lA;
      slot[33] = lB;
    }
    __syncthreads();
    if (par == 1) return;  // upper waves done; no further barriers below
#pragma unroll
    for (int jd = 0; jd < 4; ++jd) {
      accA[jd] += *(const floatx4*)(slot + jd * 4);
      accB[jd] += *(const floatx4*)(slot + 16 + jd * 4);
    }
    lA += slot[32];
    lB += slot[33];
  }

  // reduce l across the 4 lanes sharing ml (k was spread over g), invert,
  // then fetch per-output-row values (row = g*4+r lives at lane ml=g*4+r).
  lA += __shfl_xor(lA, 16); lA += __shfl_xor(lA, 32);
  lB += __shfl_xor(lB, 16); lB += __shfl_xor(lB, 32);
  const float liA = 1.0f / lA;
  const float liB = 1.0f / lB;
  float lrA[4], lrB[4];
#pragma unroll
  for (int r = 0; r < 4; ++r) {
    lrA[r] = __shfl(liA, g * 4 + r);
    lrB[r] = __shfl(liB, g * 4 + r);
  }

#pragma unroll
  for (int r = 0; r < 4; ++r) {
    const int rowA = qA0 + slice * 16 + g * 4 + r;
    const int rowB = qB0 + slice * 16 + g * 4 + r;
#pragma unroll
    for (int jd = 0; jd < 4; ++jd) {
      CTX[headoff + (size_t)rowA * D_ + jd * 16 + ml] = f2bf(accA[jd][r] * lrA[r]);
      CTX[headoff + (size_t)rowB * D_ + jd * 16 + ml] = f2bf(accB[jd][r] * lrB[r]);
    }
  }
}

// ---------------------------------------------------------------------------
extern "C" void kernel_launch(void* const* d_in, const int* in_sizes, int n_in,
                              void* d_out, int out_size, void* d_ws, size_t ws_size,
                              hipStream_t stream)
{
  const float* X  = (const float*)d_in[0];
  const float* Wq = (const float*)d_in[1];
  const float* Wk = (const float*)d_in[2];
  const float* Wv = (const float*)d_in[3];
  const float* Wo = (const float*)d_in[4];
  const float* bo = (const float*)d_in[5];

  char* ws = (char*)d_ws;
  const size_t MB = 1024 * 1024;

  unsigned short* Qb  = (unsigned short*)(ws);            // 8 MB (CTX aliases)
  unsigned short* Kb  = (unsigned short*)(ws + 8 * MB);   // 8 MB
  unsigned short* Xb  = (unsigned short*)(ws + 16 * MB);  // 8 MB
  unsigned short* WT  = (unsigned short*)(ws + 24 * MB);  // WqT|WkT|WvT|WoT
  unsigned short* WoT = WT + (size_t)3 * 1024 * 1024;
  unsigned short* Vt  = (unsigned short*)d_out;           // low 8MB of d_out
                                                          // (dead after attn;
                                                          //  wo64 overwrites)

  // merged X-convert (z=4) + 4x W transpose/convert (z=0..3)
  prep_inputs<<<dim3(32, 32, 5), dim3(32, 8), 0, stream>>>(
      X, Xb, Wq, Wk, Wv, Wo, WT);
  // fused Q/K/V projection (rolling subtile pipeline, 2D XCD chunk);
  // V -> Vt direct-transposed
  gemm256_qkv<<<dim3(24, 32), 256, 0, stream>>>(Xb, WT, Qb, Kb, Vt);
  // fused A/B, 2-phase pipelined, XCD-swizzled attention; CTX aliases Q
  attn_v16<<<dim3(512), 512, 0, stream>>>(Qb, Kb, Vt, Qb);
  // output projection + bias (64x128, BK=128 4-subtile, 512 blocks, XCD-swz)
  gemm_wo64<<<dim3(8, 64), 256, 0, stream>>>(Qb, WoT, bo, (float*)d_out);
}

// Round 14
// 177.915 us; speedup vs baseline: 1.0948x; 1.0948x over previous
//
#include <hip/hip_runtime.h>

// MultiHeadAttention: B=2, S=2048, D=1024, H=16, hd=64. fp32 I/O.
// Round 30: (1) qkv loop REVERTED to R26-exact two-subtile stage/drain
// (R29's rolling pipeline regressed 47->57us: halved staging granularity
// doubled barrier frequency per MFMA; drain coverage ~130cy < L2 latency).
// (2) qkv goes 512-thread / 8-wave (wave grid 4m x 2n, acc[2][4]/wave):
// LDS stays 32KB, grid 768 -> still 3 blocks/CU but 24 waves/CU (vs 12).
// TLP is the proven hiding mechanism for this lockstep family. Staging:
// each thread 1 gll16 per operand per subtile (512x16B = 128x32 exactly;
// dest wave*512+lane*8 == row-major [tid>>2][tid&3]).
// attn_v16, wo64, prep unchanged (best passing).

typedef __attribute__((ext_vector_type(8))) short short8;
typedef __attribute__((ext_vector_type(4))) short short4v;
typedef __attribute__((ext_vector_type(4))) float floatx4;

__device__ inline unsigned short f2bf(float f) {
  unsigned u = __float_as_uint(f);
  unsigned r = (u + 0x7fffu + ((u >> 16) & 1u)) >> 16;  // RNE
  return (unsigned short)r;
}

__device__ __forceinline__ float fast_exp2(float x) {
#if __has_builtin(__builtin_amdgcn_exp2f)
  return __builtin_amdgcn_exp2f(x);
#else
  float r;
  asm volatile("v_exp_f32_e32 %0, %1" : "=v"(r) : "v"(x));
  return r;
#endif
}

__device__ __forceinline__ void gll16(const unsigned short* g, unsigned short* l) {
  __builtin_amdgcn_global_load_lds(
      (const __attribute__((address_space(1))) unsigned int*)(g),
      (__attribute__((address_space(3))) unsigned int*)(l),
      16, 0, 0);
}

constexpr int B_ = 2, S_ = 2048, D_ = 1024, H_ = 16, HD_ = 64;

// ---------------------------------------------------------------------------
// Merged one-time converter: z=0..3 -> W transpose+convert; z=4 -> X convert.
// ---------------------------------------------------------------------------
__global__ __launch_bounds__(256) void prep_inputs(
    const float* __restrict__ x, unsigned short* __restrict__ xb,
    const float* __restrict__ w0, const float* __restrict__ w1,
    const float* __restrict__ w2, const float* __restrict__ w3,
    unsigned short* __restrict__ wt_base)
{
  if (blockIdx.z == 4) {
    const int tid = threadIdx.y * 32 + threadIdx.x;
    const size_t base =
        ((size_t)(blockIdx.y * 32 + blockIdx.x) * 256 + tid) * 16;
#pragma unroll
    for (int half = 0; half < 2; ++half) {
      const size_t i = base + half * 8;
      float4 a = *(const float4*)(x + i);
      float4 b = *(const float4*)(x + i + 4);
      short8 o;
      o[0] = (short)f2bf(a.x); o[1] = (short)f2bf(a.y);
      o[2] = (short)f2bf(a.z); o[3] = (short)f2bf(a.w);
      o[4] = (short)f2bf(b.x); o[5] = (short)f2bf(b.y);
      o[6] = (short)f2bf(b.z); o[7] = (short)f2bf(b.w);
      *(short8*)(xb + i) = o;
    }
    return;
  }
  const float* src;
  switch (blockIdx.z) {
    case 0: src = w0; break;
    case 1: src = w1; break;
    case 2: src = w2; break;
    default: src = w3; break;
  }
  unsigned short* dst = wt_base + (size_t)blockIdx.z * 1024 * 1024;
  __shared__ unsigned short t[32][33];
  const int bx = blockIdx.x * 32;  // n
  const int by = blockIdx.y * 32;  // k
  const int x_ = threadIdx.x;
  for (int yy = threadIdx.y; yy < 32; yy += 8)
    t[yy][x_] = f2bf(src[(size_t)(by + yy) * 1024 + bx + x_]);
  __syncthreads();
  for (int yy = threadIdx.y; yy < 32; yy += 8)
    dst[(size_t)(bx + yy) * 1024 + by + x_] = t[x_][yy];
}

// ---------------------------------------------------------------------------
// QKV GEMM: 128x128 tile, 512 threads / 8 waves (4m x 2n), BK=64 two-
// subtile staging (single-buffered, R26 loop), 2D XCD chunk.
// V-projection blocks write DIRECTLY transposed into Vt[(bh*64+d)][s].
// ---------------------------------------------------------------------------
__global__ __launch_bounds__(512) void gemm256_qkv(
    const unsigned short* __restrict__ A,
    const unsigned short* __restrict__ Bt,
    unsigned short* __restrict__ Qo,
    unsigned short* __restrict__ Ko,
    unsigned short* __restrict__ Vt)
{
  __shared__ unsigned short sA[2][128 * 32];
  __shared__ unsigned short sB[2][128 * 32];
  const int K = 1024;

  // 2D XCD chunk (bijective): xcd = L&7 owns rows [(xcd>>1)*8,+8) x
  // cols [(xcd&1)*12,+12), walked row-major: 12 B-panels (3MB) resident.
  const int L = blockIdx.y * 24 + blockIdx.x;
  const int xcd = L & 7, i = L >> 3;
  const int brow = (xcd >> 1) * 8 + i / 12;
  const int bcol = (xcd & 1) * 12 + i % 12;
  const int m0 = brow * 128;
  const int bn0 = bcol * 128;

  const int tid = threadIdx.x, wave = tid >> 6, lane = tid & 63;
  const int g = lane >> 4, ml = lane & 15;
  const int wm = wave & 3, wn = wave >> 2;  // 4 m-slices x 2 n-slices

  // staging: thread t covers row tid>>2 (0..127), chunk tid&3.
  const unsigned short* ag = A + (size_t)(m0 + (tid >> 2)) * K + (tid & 3) * 8;
  const unsigned short* bg = Bt + (size_t)(bn0 + (tid >> 2)) * K + (tid & 3) * 8;
  const int woff = wave * 512;  // lane*8 added by HW (wave-uniform base)

  floatx4 acc[2][4];
#pragma unroll
  for (int mt = 0; mt < 2; ++mt)
#pragma unroll
    for (int nt = 0; nt < 4; ++nt) acc[mt][nt] = (floatx4){0.f, 0.f, 0.f, 0.f};

  for (int k0 = 0; k0 < K; k0 += 64) {
    __syncthreads();
#pragma unroll
    for (int t = 0; t < 2; ++t) {
      gll16(ag + k0 + t * 32, sA[t] + woff);
      gll16(bg + k0 + t * 32, sB[t] + woff);
    }
    __syncthreads();
#pragma unroll
    for (int t = 0; t < 2; ++t) {
      short8 af[2], bf[4];
#pragma unroll
      for (int mt = 0; mt < 2; ++mt)
        af[mt] = *(const short8*)(sA[t] + (wm * 32 + mt * 16 + ml) * 32 + g * 8);
#pragma unroll
      for (int nt = 0; nt < 4; ++nt)
        bf[nt] = *(const short8*)(sB[t] + (wn * 64 + nt * 16 + ml) * 32 + g * 8);
#pragma unroll
      for (int mt = 0; mt < 2; ++mt)
#pragma unroll
        for (int nt = 0; nt < 4; ++nt)
          acc[mt][nt] = __builtin_amdgcn_mfma_f32_16x16x32_bf16(
              af[mt], bf[nt], acc[mt][nt], 0, 0, 0);
    }
  }

  const int proj = bcol >> 3;
  const int col0 = (bcol & 7) * 128;
  if (proj < 2) {
    unsigned short* out = (proj == 0) ? Qo : Ko;
#pragma unroll
    for (int mt = 0; mt < 2; ++mt) {
#pragma unroll
      for (int nt = 0; nt < 4; ++nt) {
        const int col = col0 + wn * 64 + nt * 16 + ml;
#pragma unroll
        for (int r = 0; r < 4; ++r) {
          const int row = m0 + wm * 32 + mt * 16 + g * 4 + r;
          out[(size_t)row * 1024 + col] = f2bf(acc[mt][nt][r]);
        }
      }
    }
  } else {
    // V: write transposed: Vt[((b*16+h)*64+d)*2048 + s], 4 consecutive s
    // (r=0..3) packed into one 8B store. b constant per block (128 | 2048).
    const int bq = m0 >> 11;
    const int sbase = (m0 & 2047);
#pragma unroll
    for (int mt = 0; mt < 2; ++mt) {
      const int s0 = sbase + wm * 32 + mt * 16 + g * 4;
#pragma unroll
      for (int nt = 0; nt < 4; ++nt) {
        const int col = col0 + wn * 64 + nt * 16 + ml;  // V column 0..1023
        const int h = col >> 6, d = col & 63;
        short4v o;
        o[0] = (short)f2bf(acc[mt][nt][0]);
        o[1] = (short)f2bf(acc[mt][nt][1]);
        o[2] = (short)f2bf(acc[mt][nt][2]);
        o[3] = (short)f2bf(acc[mt][nt][3]);
        *(short4v*)(Vt + ((size_t)((bq * 16 + h) * 64 + d)) * 2048 + s0) = o;
      }
    }
  }
}

// Output projection, 64x128 tile, BK=128 four-subtile staging + XCD swizzle
// (R26-exact structure).
__global__ __launch_bounds__(256) void gemm_wo64(
    const unsigned short* __restrict__ A,
    const unsigned short* __restrict__ Bt,
    const float* __restrict__ bias,
    float* __restrict__ C)
{
  __shared__ unsigned short sA[4][64 * 32];
  __shared__ unsigned short sB[4][128 * 32];
  const int K = 1024;

  // XCD swizzle (bijective: 512 % 8 == 0): 8 row-panels x 8 cols per XCD.
  const int L = blockIdx.y * 8 + blockIdx.x;
  const int rid = (L & 7) * 64 + (L >> 3);
  const int m0 = (rid >> 3) * 64;
  const int bn0 = (rid & 7) * 128;

  const int tid = threadIdx.x, wave = tid >> 6, lane = tid & 63;
  const int g = lane >> 4, ml = lane & 15;
  const int wm = wave & 1, wn = wave >> 1;

  const unsigned short* ag =
      A + (size_t)(m0 + wave * 16 + (lane >> 2)) * K + (lane & 3) * 8;
  const unsigned short* bg0 = Bt + (size_t)(bn0 + (tid >> 2)) * K + (tid & 3) * 8;
  const unsigned short* bg1 = bg0 + (size_t)64 * K;
  const int woff = wave * 512;

  floatx4 acc[2][4];
#pragma unroll
  for (int mt = 0; mt < 2; ++mt)
#pragma unroll
    for (int nt = 0; nt < 4; ++nt) acc[mt][nt] = (floatx4){0.f, 0.f, 0.f, 0.f};

  for (int k0 = 0; k0 < K; k0 += 128) {
    __syncthreads();
#pragma unroll
    for (int t = 0; t < 4; ++t) {
      gll16(ag + k0 + t * 32, sA[t] + woff);
      gll16(bg0 + k0 + t * 32, sB[t] + woff);
      gll16(bg1 + k0 + t * 32, sB[t] + 2048 + woff);
    }
    __syncthreads();
#pragma unroll
    for (int t = 0; t < 4; ++t) {
      short8 af[2], bf[4];
#pragma unroll
      for (int mt = 0; mt < 2; ++mt)
        af[mt] = *(const short8*)(sA[t] + (wm * 32 + mt * 16 + ml) * 32 + g * 8);
#pragma unroll
      for (int nt = 0; nt < 4; ++nt)
        bf[nt] = *(const short8*)(sB[t] + (wn * 64 + nt * 16 + ml) * 32 + g * 8);
#pragma unroll
      for (int mt = 0; mt < 2; ++mt)
#pragma unroll
        for (int nt = 0; nt < 4; ++nt)
          acc[mt][nt] = __builtin_amdgcn_mfma_f32_16x16x32_bf16(
              af[mt], bf[nt], acc[mt][nt], 0, 0, 0);
    }
  }

#pragma unroll
  for (int mt = 0; mt < 2; ++mt) {
#pragma unroll
    for (int nt = 0; nt < 4; ++nt) {
      const int col = bn0 + wn * 64 + nt * 16 + ml;
      const float badd = bias[col];
#pragma unroll
      for (int r = 0; r < 4; ++r) {
        const int row = m0 + wm * 32 + mt * 16 + g * 4 + r;
        C[(size_t)row * 1024 + col] = acc[mt][nt][r] + badd;
      }
    }
  }
}

// ---------------------------------------------------------------------------
// Attention v16 (unchanged, best passing): 8-wave parity split, fused A/B
// dual-tile, K+V LDS staging, 2-phase pipeline, in-register softmax,
// raw-f32 l partials, setprio around MFMA clusters. Runtime diag bools.
// LDS: 2 bufs x 2 tiles x (K 8KB + V 8KB) = 64KB; union comb 36KB.
// ---------------------------------------------------------------------------
constexpr int KTPB = 2;  // k-tiles per buffer group

struct AttnLds {
  unsigned short k0[2][KTPB][64 * 32];
  unsigned short k1[2][KTPB][64 * 32];
  unsigned short v0[2][KTPB][64 * 32];
  unsigned short v1[2][KTPB][64 * 32];
};
union __align__(16) AttnLdsU {
  AttnLds t;
  float comb[4 * 64 * 36];  // 36 KB <= 64 KB; used after last barrier
};

// softmax + pack + permlane redistribute: s -> ap[2] (PV A-frags).
// l sums RAW f32 (4 partials); v_perm byte-select truncates P to bf16.
__device__ __forceinline__ void softmax_pack(
    const floatx4* s, const bool diag, const int qg, const int kb,
    float& l, short8* ap)
{
  const float C1 = 0.18033688f;    // 0.125 / ln2
  const float C2 = -34.6246810f;   // -24 / ln2

  unsigned wb[4][4];
  float lp0 = 0.f, lp1 = 0.f, lp2 = 0.f, lp3 = 0.f;
#pragma unroll
  for (int nb = 0; nb < 4; ++nb) {
#pragma unroll
    for (int r = 0; r < 4; ++r) {
      float wv = fast_exp2(fmaf(s[nb][r], C1, C2));
      if (diag && (kb + nb * 16 + r > qg)) wv = 0.f;
      wb[nb][r] = __float_as_uint(wv);
      if (nb == 0) lp0 += wv;
      else if (nb == 1) lp1 += wv;
      else if (nb == 2) lp2 += wv;
      else lp3 += wv;
    }
  }
  l += (lp0 + lp1) + (lp2 + lp3);

  // pack pairs along r (v_perm bytes 2,3 of each source = truncated bf16)
  unsigned pk[4][2];
#pragma unroll
  for (int nb = 0; nb < 4; ++nb) {
    pk[nb][0] = __builtin_amdgcn_perm(wb[nb][1], wb[nb][0], 0x07060302u);
    pk[nb][1] = __builtin_amdgcn_perm(wb[nb][3], wb[nb][2], 0x07060302u);
  }

  // redistribute to PV A-frag: 2x permlane32_swap + 2x permlane16_swap per rr
  unsigned Fr[2][4];
#pragma unroll
  for (int rr = 0; rr < 2; ++rr) {
    unsigned a0 = pk[0][rr], a1 = pk[1][rr];
    unsigned a2 = pk[2][rr], a3 = pk[3][rr];
    asm("v_permlane32_swap_b32 %0, %1" : "+v"(a0), "+v"(a1));
    asm("v_permlane32_swap_b32 %0, %1" : "+v"(a2), "+v"(a3));
    asm("v_permlane16_swap_b32 %0, %1" : "+v"(a0), "+v"(a1));
    asm("v_permlane16_swap_b32 %0, %1" : "+v"(a2), "+v"(a3));
    Fr[0][rr] = a0; Fr[0][2 + rr] = a1;
    Fr[1][rr] = a2; Fr[1][2 + rr] = a3;
  }
#pragma unroll
  for (int f = 0; f < 2; ++f) {
    union { unsigned u[4]; short8 s8; } uap;
    uap.u[0] = Fr[f][0]; uap.u[1] = Fr[f][1];
    uap.u[2] = Fr[f][2]; uap.u[3] = Fr[f][3];
    ap[f] = uap.s8;
  }
}

// Fused dual-q-block tile: K/V fragments read ONCE, feed both MFMA chains.
template <bool DUAL>
__device__ __forceinline__ void attn_tile2(
    const short8* aqB, const short8* aqA,
    const unsigned short* sK0, const unsigned short* sK1,
    const unsigned short* sV0, const unsigned short* sV1,
    floatx4* accB, float& lB, floatx4* accA, float& lA,
    const bool diagB, const bool diagA,
    const int qgB, const int qgA, const int kb,
    const int g, const int ml)
{
  floatx4 sB[4], sA[4];
  __builtin_amdgcn_s_setprio(1);
#pragma unroll
  for (int nb = 0; nb < 4; ++nb) {
    short8 bk0 = *(const short8*)(sK0 + (nb * 16 + ml) * 32 + g * 8);
    short8 bk1 = *(const short8*)(sK1 + (nb * 16 + ml) * 32 + g * 8);
    sB[nb] = (floatx4){0.f, 0.f, 0.f, 0.f};
    sB[nb] = __builtin_amdgcn_mfma_f32_16x16x32_bf16(bk0, aqB[0], sB[nb], 0, 0, 0);
    sB[nb] = __builtin_amdgcn_mfma_f32_16x16x32_bf16(bk1, aqB[1], sB[nb], 0, 0, 0);
    if (DUAL) {
      sA[nb] = (floatx4){0.f, 0.f, 0.f, 0.f};
      sA[nb] = __builtin_amdgcn_mfma_f32_16x16x32_bf16(bk0, aqA[0], sA[nb], 0, 0, 0);
      sA[nb] = __builtin_amdgcn_mfma_f32_16x16x32_bf16(bk1, aqA[1], sA[nb], 0, 0, 0);
    }
  }
  __builtin_amdgcn_s_setprio(0);

  short8 apB[2], apA[2];
  softmax_pack(sB, diagB, qgB, kb, lB, apB);
  if (DUAL) softmax_pack(sA, diagA, qgA, kb, lA, apA);

  __builtin_amdgcn_s_setprio(1);
#pragma unroll
  for (int f = 0; f < 2; ++f) {
    const unsigned short* sv = f ? sV1 : sV0;
#pragma unroll
    for (int jd = 0; jd < 4; ++jd) {
      short8 bv = *(const short8*)(sv + (jd * 16 + ml) * 32 + g * 8);
      accB[jd] = __builtin_amdgcn_mfma_f32_16x16x32_bf16(apB[f], bv, accB[jd], 0, 0, 0);
      if (DUAL)
        accA[jd] = __builtin_amdgcn_mfma_f32_16x16x32_bf16(apA[f], bv, accA[jd], 0, 0, 0);
    }
  }
  __builtin_amdgcn_s_setprio(0);
}

__global__ __launch_bounds__(512) void attn_v16(
    const unsigned short* __restrict__ Q,
    const unsigned short* __restrict__ Kg,
    const unsigned short* __restrict__ Vt,
    unsigned short* __restrict__ CTX)
{
  __shared__ AttnLdsU lds;

  // XCD-chunked swizzle (bijective: 512 % 8 == 0): groups 4 consecutive bh
  // per XCD -> K/V working set 2MB < 4MB L2.
  const int L = blockIdx.x;
  const int rid = (L & 7) * 64 + (L >> 3);
  const int p = rid & 15;
  const int bh = rid >> 4;

  const int b = bh >> 4, h = bh & 15;
  const int qbA = p, qbB = 31 - p;
  const int qA0 = qbA * 64, qB0 = qbB * 64;
  const int tid = threadIdx.x, w = tid >> 6, lane = tid & 63;
  const int slice = w & 3, par = w >> 2;
  const int g = lane >> 4, ml = lane & 15;

  const size_t headoff = (size_t)b * S_ * D_ + (size_t)h * HD_;
  const size_t vtoff   = (size_t)bh * HD_ * S_;

  short8 aqA[2], aqB[2];
  {
    const unsigned short* qp =
        Q + headoff + (size_t)(qA0 + slice * 16 + ml) * D_ + g * 8;
    aqA[0] = *(const short8*)qp;
    aqA[1] = *(const short8*)(qp + 32);
  }
  {
    const unsigned short* qp =
        Q + headoff + (size_t)(qB0 + slice * 16 + ml) * D_ + g * 8;
    aqB[0] = *(const short8*)qp;
    aqB[1] = *(const short8*)(qp + 32);
  }

  floatx4 accA[4], accB[4];
#pragma unroll
  for (int jd = 0; jd < 4; ++jd) {
    accA[jd] = (floatx4){0.f, 0.f, 0.f, 0.f};
    accB[jd] = (floatx4){0.f, 0.f, 0.f, 0.f};
  }
  float lA = 0.f, lB = 0.f;
  const int qgA = qA0 + slice * 16 + ml;   // this lane's q-row (A block)
  const int qgB = qB0 + slice * 16 + ml;

  // staging: waves 0-3 handle K, waves 4-7 handle V; each covers 16 rows.
  const int sw = slice;
  const unsigned short* kgb =
      Kg + headoff + (size_t)(sw * 16 + (lane >> 2)) * D_ + (lane & 3) * 8;
  const unsigned short* vgb =
      Vt + vtoff + (size_t)(sw * 16 + (lane >> 2)) * S_ + (lane & 3) * 8;
  const int woff = sw * 512;

  const int ntiles = qbB + 1;

  // ---- stage group 0 into buf 0 (prologue; one unhidden drain) ----
  {
    const int cnt = (ntiles < KTPB) ? ntiles : KTPB;
#pragma unroll
    for (int t = 0; t < KTPB; ++t) {
      if (t >= cnt) break;
      if (w < 4) {
        const size_t ko = (size_t)t * 64 * D_;
        gll16(kgb + ko,      lds.t.k0[0][t] + woff);
        gll16(kgb + ko + 32, lds.t.k1[0][t] + woff);
      } else {
        gll16(vgb + t * 64,      lds.t.v0[0][t] + woff);
        gll16(vgb + t * 64 + 32, lds.t.v1[0][t] + woff);
      }
    }
  }
  __syncthreads();

  for (int kt0 = 0; kt0 < ntiles; kt0 += KTPB) {
    const int bufi = (kt0 >> 1) & 1;
    // ---- stage NEXT group into buf^1 (issue early; drained at barrier) ----
    const int nxt = kt0 + KTPB;
    if (nxt < ntiles) {
      const int cn = (ntiles - nxt < KTPB) ? (ntiles - nxt) : KTPB;
#pragma unroll
      for (int t = 0; t < KTPB; ++t) {
        if (t >= cn) break;
        const int kt = nxt + t;
        if (w < 4) {
          const size_t ko = (size_t)kt * 64 * D_;
          gll16(kgb + ko,      lds.t.k0[bufi ^ 1][t] + woff);
          gll16(kgb + ko + 32, lds.t.k1[bufi ^ 1][t] + woff);
        } else {
          gll16(vgb + kt * 64,      lds.t.v0[bufi ^ 1][t] + woff);
          gll16(vgb + kt * 64 + 32, lds.t.v1[bufi ^ 1][t] + woff);
        }
      }
    }

    // ---- compute current buf (A/B fused when both in causal range) ----
    const int cnt = (ntiles - kt0 < KTPB) ? (ntiles - kt0) : KTPB;  // uniform
    if (par < cnt) {
      const int kt = kt0 + par;
      const int kb = kt * 64 + g * 4;
      if (kt <= qbA)
        attn_tile2<true>(aqB, aqA,
                         lds.t.k0[bufi][par], lds.t.k1[bufi][par],
                         lds.t.v0[bufi][par], lds.t.v1[bufi][par],
                         accB, lB, accA, lA,
                         kt == qbB, kt == qbA, qgB, qgA, kb, g, ml);
      else
        attn_tile2<false>(aqB, aqA,
                          lds.t.k0[bufi][par], lds.t.k1[bufi][par],
                          lds.t.v0[bufi][par], lds.t.v1[bufi][par],
                          accB, lB, accA, lA,
                          kt == qbB, false, qgB, qgA, kb, g, ml);
    }
    __syncthreads();  // drains next-group loads (hidden under compute)
  }

  // ---- combine parity pairs (w, w+4) through LDS ----
  {
    float* slot = lds.comb + (size_t)(slice * 64 + lane) * 36;
    if (par == 1) {
#pragma unroll
      for (int jd = 0; jd < 4; ++jd) {
        *(floatx4*)(slot + jd * 4) = accA[jd];
        *(floatx4*)(slot + 16 + jd * 4) = accB[jd];
      }
      slot[32] = lA;
      slot[33] = lB;
    }
    __syncthreads();
    if (par == 1) return;  // upper waves done; no further barriers below
#pragma unroll
    for (int jd = 0; jd < 4; ++jd) {
      accA[jd] += *(const floatx4*)(slot + jd * 4);
      accB[jd] += *(const floatx4*)(slot + 16 + jd * 4);
    }
    lA += slot[32];
    lB += slot[33];
  }

  // reduce l across the 4 lanes sharing ml (k was spread over g), invert,
  // then fetch per-output-row values (row = g*4+r lives at lane ml=g*4+r).
  lA += __shfl_xor(lA, 16); lA += __shfl_xor(lA, 32);
  lB += __shfl_xor(lB, 16); lB += __shfl_xor(lB, 32);
  const float liA = 1.0f / lA;
  const float liB = 1.0f / lB;
  float lrA[4], lrB[4];
#pragma unroll
  for (int r = 0; r < 4; ++r) {
    lrA[r] = __shfl(liA, g * 4 + r);
    lrB[r] = __shfl(liB, g * 4 + r);
  }

#pragma unroll
  for (int r = 0; r < 4; ++r) {
    const int rowA = qA0 + slice * 16 + g * 4 + r;
    const int rowB = qB0 + slice * 16 + g * 4 + r;
#pragma unroll
    for (int jd = 0; jd < 4; ++jd) {
      CTX[headoff + (size_t)rowA * D_ + jd * 16 + ml] = f2bf(accA[jd][r] * lrA[r]);
      CTX[headoff + (size_t)rowB * D_ + jd * 16 + ml] = f2bf(accB[jd][r] * lrB[r]);
    }
  }
}

// ---------------------------------------------------------------------------
extern "C" void kernel_launch(void* const* d_in, const int* in_sizes, int n_in,
                              void* d_out, int out_size, void* d_ws, size_t ws_size,
                              hipStream_t stream)
{
  const float* X  = (const float*)d_in[0];
  const float* Wq = (const float*)d_in[1];
  const float* Wk = (const float*)d_in[2];
  const float* Wv = (const float*)d_in[3];
  const float* Wo = (const float*)d_in[4];
  const float* bo = (const float*)d_in[5];

  char* ws = (char*)d_ws;
  const size_t MB = 1024 * 1024;

  unsigned short* Qb  = (unsigned short*)(ws);            // 8 MB (CTX aliases)
  unsigned short* Kb  = (unsigned short*)(ws + 8 * MB);   // 8 MB
  unsigned short* Xb  = (unsigned short*)(ws + 16 * MB);  // 8 MB
  unsigned short* WT  = (unsigned short*)(ws + 24 * MB);  // WqT|WkT|WvT|WoT
  unsigned short* WoT = WT + (size_t)3 * 1024 * 1024;
  unsigned short* Vt  = (unsigned short*)d_out;           // low 8MB of d_out
                                                          // (dead after attn;
                                                          //  wo64 overwrites)

  // merged X-convert (z=4) + 4x W transpose/convert (z=0..3)
  prep_inputs<<<dim3(32, 32, 5), dim3(32, 8), 0, stream>>>(
      X, Xb, Wq, Wk, Wv, Wo, WT);
  // fused Q/K/V projection (512-thread 8-wave, 2D XCD chunk); V -> Vt direct
  gemm256_qkv<<<dim3(24, 32), 512, 0, stream>>>(Xb, WT, Qb, Kb, Vt);
  // fused A/B, 2-phase pipelined, XCD-swizzled attention; CTX aliases Q
  attn_v16<<<dim3(512), 512, 0, stream>>>(Qb, Kb, Vt, Qb);
  // output projection + bias (64x128, BK=128 4-subtile, 512 blocks, XCD-swz)
  gemm_wo64<<<dim3(8, 64), 256, 0, stream>>>(Qb, WoT, bo, (float*)d_out);
}

// Round 15
// 177.136 us; speedup vs baseline: 1.0996x; 1.0044x over previous
//
#include <hip/hip_runtime.h>

// MultiHeadAttention: B=2, S=2048, D=1024, H=16, hd=64. fp32 I/O.
// Round 31: gemm_wo64 gets the R30-proven 8-wave TLP transform (the same
// lever that took qkv out of the top-5): 512 threads / 8 waves on the
// 64x128 tile (wm=wave&1, wn=wave>>1; per-wave 32x32, acc[2][2]), BK=64
// two-subtile single-buffered staging, LDS 24KB, grid 512 -> 16 waves/CU
// (was 8). Staging: A 1 gll16/thread, B 2 (exact cover; dest q*512+lane*8
// == [q*16+(lane>>2)][lane&3]). qkv (R30 8-wave), attn_v16, prep unchanged.

typedef __attribute__((ext_vector_type(8))) short short8;
typedef __attribute__((ext_vector_type(4))) short short4v;
typedef __attribute__((ext_vector_type(4))) float floatx4;

__device__ inline unsigned short f2bf(float f) {
  unsigned u = __float_as_uint(f);
  unsigned r = (u + 0x7fffu + ((u >> 16) & 1u)) >> 16;  // RNE
  return (unsigned short)r;
}

__device__ __forceinline__ float fast_exp2(float x) {
#if __has_builtin(__builtin_amdgcn_exp2f)
  return __builtin_amdgcn_exp2f(x);
#else
  float r;
  asm volatile("v_exp_f32_e32 %0, %1" : "=v"(r) : "v"(x));
  return r;
#endif
}

__device__ __forceinline__ void gll16(const unsigned short* g, unsigned short* l) {
  __builtin_amdgcn_global_load_lds(
      (const __attribute__((address_space(1))) unsigned int*)(g),
      (__attribute__((address_space(3))) unsigned int*)(l),
      16, 0, 0);
}

constexpr int B_ = 2, S_ = 2048, D_ = 1024, H_ = 16, HD_ = 64;

// ---------------------------------------------------------------------------
// Merged one-time converter: z=0..3 -> W transpose+convert; z=4 -> X convert.
// ---------------------------------------------------------------------------
__global__ __launch_bounds__(256) void prep_inputs(
    const float* __restrict__ x, unsigned short* __restrict__ xb,
    const float* __restrict__ w0, const float* __restrict__ w1,
    const float* __restrict__ w2, const float* __restrict__ w3,
    unsigned short* __restrict__ wt_base)
{
  if (blockIdx.z == 4) {
    const int tid = threadIdx.y * 32 + threadIdx.x;
    const size_t base =
        ((size_t)(blockIdx.y * 32 + blockIdx.x) * 256 + tid) * 16;
#pragma unroll
    for (int half = 0; half < 2; ++half) {
      const size_t i = base + half * 8;
      float4 a = *(const float4*)(x + i);
      float4 b = *(const float4*)(x + i + 4);
      short8 o;
      o[0] = (short)f2bf(a.x); o[1] = (short)f2bf(a.y);
      o[2] = (short)f2bf(a.z); o[3] = (short)f2bf(a.w);
      o[4] = (short)f2bf(b.x); o[5] = (short)f2bf(b.y);
      o[6] = (short)f2bf(b.z); o[7] = (short)f2bf(b.w);
      *(short8*)(xb + i) = o;
    }
    return;
  }
  const float* src;
  switch (blockIdx.z) {
    case 0: src = w0; break;
    case 1: src = w1; break;
    case 2: src = w2; break;
    default: src = w3; break;
  }
  unsigned short* dst = wt_base + (size_t)blockIdx.z * 1024 * 1024;
  __shared__ unsigned short t[32][33];
  const int bx = blockIdx.x * 32;  // n
  const int by = blockIdx.y * 32;  // k
  const int x_ = threadIdx.x;
  for (int yy = threadIdx.y; yy < 32; yy += 8)
    t[yy][x_] = f2bf(src[(size_t)(by + yy) * 1024 + bx + x_]);
  __syncthreads();
  for (int yy = threadIdx.y; yy < 32; yy += 8)
    dst[(size_t)(bx + yy) * 1024 + by + x_] = t[x_][yy];
}

// ---------------------------------------------------------------------------
// QKV GEMM (R30-exact): 128x128 tile, 512 threads / 8 waves (4m x 2n),
// BK=64 two-subtile staging, 2D XCD chunk. V written transposed into Vt.
// ---------------------------------------------------------------------------
__global__ __launch_bounds__(512) void gemm256_qkv(
    const unsigned short* __restrict__ A,
    const unsigned short* __restrict__ Bt,
    unsigned short* __restrict__ Qo,
    unsigned short* __restrict__ Ko,
    unsigned short* __restrict__ Vt)
{
  __shared__ unsigned short sA[2][128 * 32];
  __shared__ unsigned short sB[2][128 * 32];
  const int K = 1024;

  // 2D XCD chunk (bijective): xcd = L&7 owns rows [(xcd>>1)*8,+8) x
  // cols [(xcd&1)*12,+12), walked row-major: 12 B-panels (3MB) resident.
  const int L = blockIdx.y * 24 + blockIdx.x;
  const int xcd = L & 7, i = L >> 3;
  const int brow = (xcd >> 1) * 8 + i / 12;
  const int bcol = (xcd & 1) * 12 + i % 12;
  const int m0 = brow * 128;
  const int bn0 = bcol * 128;

  const int tid = threadIdx.x, wave = tid >> 6, lane = tid & 63;
  const int g = lane >> 4, ml = lane & 15;
  const int wm = wave & 3, wn = wave >> 2;  // 4 m-slices x 2 n-slices

  // staging: thread t covers row tid>>2 (0..127), chunk tid&3.
  const unsigned short* ag = A + (size_t)(m0 + (tid >> 2)) * K + (tid & 3) * 8;
  const unsigned short* bg = Bt + (size_t)(bn0 + (tid >> 2)) * K + (tid & 3) * 8;
  const int woff = wave * 512;  // lane*8 added by HW (wave-uniform base)

  floatx4 acc[2][4];
#pragma unroll
  for (int mt = 0; mt < 2; ++mt)
#pragma unroll
    for (int nt = 0; nt < 4; ++nt) acc[mt][nt] = (floatx4){0.f, 0.f, 0.f, 0.f};

  for (int k0 = 0; k0 < K; k0 += 64) {
    __syncthreads();
#pragma unroll
    for (int t = 0; t < 2; ++t) {
      gll16(ag + k0 + t * 32, sA[t] + woff);
      gll16(bg + k0 + t * 32, sB[t] + woff);
    }
    __syncthreads();
#pragma unroll
    for (int t = 0; t < 2; ++t) {
      short8 af[2], bf[4];
#pragma unroll
      for (int mt = 0; mt < 2; ++mt)
        af[mt] = *(const short8*)(sA[t] + (wm * 32 + mt * 16 + ml) * 32 + g * 8);
#pragma unroll
      for (int nt = 0; nt < 4; ++nt)
        bf[nt] = *(const short8*)(sB[t] + (wn * 64 + nt * 16 + ml) * 32 + g * 8);
#pragma unroll
      for (int mt = 0; mt < 2; ++mt)
#pragma unroll
        for (int nt = 0; nt < 4; ++nt)
          acc[mt][nt] = __builtin_amdgcn_mfma_f32_16x16x32_bf16(
              af[mt], bf[nt], acc[mt][nt], 0, 0, 0);
    }
  }

  const int proj = bcol >> 3;
  const int col0 = (bcol & 7) * 128;
  if (proj < 2) {
    unsigned short* out = (proj == 0) ? Qo : Ko;
#pragma unroll
    for (int mt = 0; mt < 2; ++mt) {
#pragma unroll
      for (int nt = 0; nt < 4; ++nt) {
        const int col = col0 + wn * 64 + nt * 16 + ml;
#pragma unroll
        for (int r = 0; r < 4; ++r) {
          const int row = m0 + wm * 32 + mt * 16 + g * 4 + r;
          out[(size_t)row * 1024 + col] = f2bf(acc[mt][nt][r]);
        }
      }
    }
  } else {
    // V: write transposed: Vt[((b*16+h)*64+d)*2048 + s], 4 consecutive s
    // (r=0..3) packed into one 8B store. b constant per block (128 | 2048).
    const int bq = m0 >> 11;
    const int sbase = (m0 & 2047);
#pragma unroll
    for (int mt = 0; mt < 2; ++mt) {
      const int s0 = sbase + wm * 32 + mt * 16 + g * 4;
#pragma unroll
      for (int nt = 0; nt < 4; ++nt) {
        const int col = col0 + wn * 64 + nt * 16 + ml;  // V column 0..1023
        const int h = col >> 6, d = col & 63;
        short4v o;
        o[0] = (short)f2bf(acc[mt][nt][0]);
        o[1] = (short)f2bf(acc[mt][nt][1]);
        o[2] = (short)f2bf(acc[mt][nt][2]);
        o[3] = (short)f2bf(acc[mt][nt][3]);
        *(short4v*)(Vt + ((size_t)((bq * 16 + h) * 64 + d)) * 2048 + s0) = o;
      }
    }
  }
}

// ---------------------------------------------------------------------------
// Output projection: 64x128 tile, 512 threads / 8 waves (2m x 4n, 32x32
// per wave), BK=64 two-subtile staging (24KB LDS), XCD swizzle.
// A: 1 gll16/thread (wave w -> subtile w>>2, quarter w&3);
// B: 2 gll16/thread (chunks c=2w+h -> subtile c>>3, eighth c&7).
// ---------------------------------------------------------------------------
__global__ __launch_bounds__(512) void gemm_wo64(
    const unsigned short* __restrict__ A,
    const unsigned short* __restrict__ Bt,
    const float* __restrict__ bias,
    float* __restrict__ C)
{
  __shared__ unsigned short sA[2][64 * 32];   // 4KB each
  __shared__ unsigned short sB[2][128 * 32];  // 8KB each -> 24KB total
  const int K = 1024;

  // XCD swizzle (bijective: 512 % 8 == 0): 8 row-panels x 8 cols per XCD.
  const int L = blockIdx.y * 8 + blockIdx.x;
  const int rid = (L & 7) * 64 + (L >> 3);
  const int m0 = (rid >> 3) * 64;
  const int bn0 = (rid & 7) * 128;

  const int tid = threadIdx.x, wave = tid >> 6, lane = tid & 63;
  const int g = lane >> 4, ml = lane & 15;
  const int wm = wave & 1, wn = wave >> 1;  // 2 m-slices x 4 n-slices

  // A staging: wave w -> subtile sa=w>>2, quarter qa=w&3.
  const int sa = wave >> 2, qa = wave & 3;
  const unsigned short* ag =
      A + (size_t)(m0 + qa * 16 + (lane >> 2)) * K + sa * 32 + (lane & 3) * 8;
  unsigned short* const adst = sA[sa] + qa * 512;
  // B staging: chunks c = 2*wave + h (h=0,1): subtile c>>3, eighth c&7.
  const int c0 = wave * 2, c1 = wave * 2 + 1;
  const unsigned short* bg0 =
      Bt + (size_t)(bn0 + (c0 & 7) * 16 + (lane >> 2)) * K + (c0 >> 3) * 32 + (lane & 3) * 8;
  const unsigned short* bg1 =
      Bt + (size_t)(bn0 + (c1 & 7) * 16 + (lane >> 2)) * K + (c1 >> 3) * 32 + (lane & 3) * 8;
  unsigned short* const bdst0 = sB[c0 >> 3] + (c0 & 7) * 512;
  unsigned short* const bdst1 = sB[c1 >> 3] + (c1 & 7) * 512;

  floatx4 acc[2][2];
#pragma unroll
  for (int mt = 0; mt < 2; ++mt)
#pragma unroll
    for (int nt = 0; nt < 2; ++nt) acc[mt][nt] = (floatx4){0.f, 0.f, 0.f, 0.f};

  for (int k0 = 0; k0 < K; k0 += 64) {
    __syncthreads();
    gll16(ag + k0, adst);
    gll16(bg0 + k0, bdst0);
    gll16(bg1 + k0, bdst1);
    __syncthreads();
#pragma unroll
    for (int t = 0; t < 2; ++t) {
      short8 af[2], bf[2];
#pragma unroll
      for (int mt = 0; mt < 2; ++mt)
        af[mt] = *(const short8*)(sA[t] + (wm * 32 + mt * 16 + ml) * 32 + g * 8);
#pragma unroll
      for (int nt = 0; nt < 2; ++nt)
        bf[nt] = *(const short8*)(sB[t] + (wn * 32 + nt * 16 + ml) * 32 + g * 8);
#pragma unroll
      for (int mt = 0; mt < 2; ++mt)
#pragma unroll
        for (int nt = 0; nt < 2; ++nt)
          acc[mt][nt] = __builtin_amdgcn_mfma_f32_16x16x32_bf16(
              af[mt], bf[nt], acc[mt][nt], 0, 0, 0);
    }
  }

#pragma unroll
  for (int mt = 0; mt < 2; ++mt) {
#pragma unroll
    for (int nt = 0; nt < 2; ++nt) {
      const int col = bn0 + wn * 32 + nt * 16 + ml;
      const float badd = bias[col];
#pragma unroll
      for (int r = 0; r < 4; ++r) {
        const int row = m0 + wm * 32 + mt * 16 + g * 4 + r;
        C[(size_t)row * 1024 + col] = acc[mt][nt][r] + badd;
      }
    }
  }
}

// ---------------------------------------------------------------------------
// Attention v16 (unchanged, best passing): 8-wave parity split, fused A/B
// dual-tile, K+V LDS staging, 2-phase pipeline, in-register softmax,
// raw-f32 l partials, setprio around MFMA clusters. Runtime diag bools.
// LDS: 2 bufs x 2 tiles x (K 8KB + V 8KB) = 64KB; union comb 36KB.
// ---------------------------------------------------------------------------
constexpr int KTPB = 2;  // k-tiles per buffer group

struct AttnLds {
  unsigned short k0[2][KTPB][64 * 32];
  unsigned short k1[2][KTPB][64 * 32];
  unsigned short v0[2][KTPB][64 * 32];
  unsigned short v1[2][KTPB][64 * 32];
};
union __align__(16) AttnLdsU {
  AttnLds t;
  float comb[4 * 64 * 36];  // 36 KB <= 64 KB; used after last barrier
};

// softmax + pack + permlane redistribute: s -> ap[2] (PV A-frags).
// l sums RAW f32 (4 partials); v_perm byte-select truncates P to bf16.
__device__ __forceinline__ void softmax_pack(
    const floatx4* s, const bool diag, const int qg, const int kb,
    float& l, short8* ap)
{
  const float C1 = 0.18033688f;    // 0.125 / ln2
  const float C2 = -34.6246810f;   // -24 / ln2

  unsigned wb[4][4];
  float lp0 = 0.f, lp1 = 0.f, lp2 = 0.f, lp3 = 0.f;
#pragma unroll
  for (int nb = 0; nb < 4; ++nb) {
#pragma unroll
    for (int r = 0; r < 4; ++r) {
      float wv = fast_exp2(fmaf(s[nb][r], C1, C2));
      if (diag && (kb + nb * 16 + r > qg)) wv = 0.f;
      wb[nb][r] = __float_as_uint(wv);
      if (nb == 0) lp0 += wv;
      else if (nb == 1) lp1 += wv;
      else if (nb == 2) lp2 += wv;
      else lp3 += wv;
    }
  }
  l += (lp0 + lp1) + (lp2 + lp3);

  // pack pairs along r (v_perm bytes 2,3 of each source = truncated bf16)
  unsigned pk[4][2];
#pragma unroll
  for (int nb = 0; nb < 4; ++nb) {
    pk[nb][0] = __builtin_amdgcn_perm(wb[nb][1], wb[nb][0], 0x07060302u);
    pk[nb][1] = __builtin_amdgcn_perm(wb[nb][3], wb[nb][2], 0x07060302u);
  }

  // redistribute to PV A-frag: 2x permlane32_swap + 2x permlane16_swap per rr
  unsigned Fr[2][4];
#pragma unroll
  for (int rr = 0; rr < 2; ++rr) {
    unsigned a0 = pk[0][rr], a1 = pk[1][rr];
    unsigned a2 = pk[2][rr], a3 = pk[3][rr];
    asm("v_permlane32_swap_b32 %0, %1" : "+v"(a0), "+v"(a1));
    asm("v_permlane32_swap_b32 %0, %1" : "+v"(a2), "+v"(a3));
    asm("v_permlane16_swap_b32 %0, %1" : "+v"(a0), "+v"(a1));
    asm("v_permlane16_swap_b32 %0, %1" : "+v"(a2), "+v"(a3));
    Fr[0][rr] = a0; Fr[0][2 + rr] = a1;
    Fr[1][rr] = a2; Fr[1][2 + rr] = a3;
  }
#pragma unroll
  for (int f = 0; f < 2; ++f) {
    union { unsigned u[4]; short8 s8; } uap;
    uap.u[0] = Fr[f][0]; uap.u[1] = Fr[f][1];
    uap.u[2] = Fr[f][2]; uap.u[3] = Fr[f][3];
    ap[f] = uap.s8;
  }
}

// Fused dual-q-block tile: K/V fragments read ONCE, feed both MFMA chains.
template <bool DUAL>
__device__ __forceinline__ void attn_tile2(
    const short8* aqB, const short8* aqA,
    const unsigned short* sK0, const unsigned short* sK1,
    const unsigned short* sV0, const unsigned short* sV1,
    floatx4* accB, float& lB, floatx4* accA, float& lA,
    const bool diagB, const bool diagA,
    const int qgB, const int qgA, const int kb,
    const int g, const int ml)
{
  floatx4 sB[4], sA[4];
  __builtin_amdgcn_s_setprio(1);
#pragma unroll
  for (int nb = 0; nb < 4; ++nb) {
    short8 bk0 = *(const short8*)(sK0 + (nb * 16 + ml) * 32 + g * 8);
    short8 bk1 = *(const short8*)(sK1 + (nb * 16 + ml) * 32 + g * 8);
    sB[nb] = (floatx4){0.f, 0.f, 0.f, 0.f};
    sB[nb] = __builtin_amdgcn_mfma_f32_16x16x32_bf16(bk0, aqB[0], sB[nb], 0, 0, 0);
    sB[nb] = __builtin_amdgcn_mfma_f32_16x16x32_bf16(bk1, aqB[1], sB[nb], 0, 0, 0);
    if (DUAL) {
      sA[nb] = (floatx4){0.f, 0.f, 0.f, 0.f};
      sA[nb] = __builtin_amdgcn_mfma_f32_16x16x32_bf16(bk0, aqA[0], sA[nb], 0, 0, 0);
      sA[nb] = __builtin_amdgcn_mfma_f32_16x16x32_bf16(bk1, aqA[1], sA[nb], 0, 0, 0);
    }
  }
  __builtin_amdgcn_s_setprio(0);

  short8 apB[2], apA[2];
  softmax_pack(sB, diagB, qgB, kb, lB, apB);
  if (DUAL) softmax_pack(sA, diagA, qgA, kb, lA, apA);

  __builtin_amdgcn_s_setprio(1);
#pragma unroll
  for (int f = 0; f < 2; ++f) {
    const unsigned short* sv = f ? sV1 : sV0;
#pragma unroll
    for (int jd = 0; jd < 4; ++jd) {
      short8 bv = *(const short8*)(sv + (jd * 16 + ml) * 32 + g * 8);
      accB[jd] = __builtin_amdgcn_mfma_f32_16x16x32_bf16(apB[f], bv, accB[jd], 0, 0, 0);
      if (DUAL)
        accA[jd] = __builtin_amdgcn_mfma_f32_16x16x32_bf16(apA[f], bv, accA[jd], 0, 0, 0);
    }
  }
  __builtin_amdgcn_s_setprio(0);
}

__global__ __launch_bounds__(512) void attn_v16(
    const unsigned short* __restrict__ Q,
    const unsigned short* __restrict__ Kg,
    const unsigned short* __restrict__ Vt,
    unsigned short* __restrict__ CTX)
{
  __shared__ AttnLdsU lds;

  // XCD-chunked swizzle (bijective: 512 % 8 == 0): groups 4 consecutive bh
  // per XCD -> K/V working set 2MB < 4MB L2.
  const int L = blockIdx.x;
  const int rid = (L & 7) * 64 + (L >> 3);
  const int p = rid & 15;
  const int bh = rid >> 4;

  const int b = bh >> 4, h = bh & 15;
  const int qbA = p, qbB = 31 - p;
  const int qA0 = qbA * 64, qB0 = qbB * 64;
  const int tid = threadIdx.x, w = tid >> 6, lane = tid & 63;
  const int slice = w & 3, par = w >> 2;
  const int g = lane >> 4, ml = lane & 15;

  const size_t headoff = (size_t)b * S_ * D_ + (size_t)h * HD_;
  const size_t vtoff   = (size_t)bh * HD_ * S_;

  short8 aqA[2], aqB[2];
  {
    const unsigned short* qp =
        Q + headoff + (size_t)(qA0 + slice * 16 + ml) * D_ + g * 8;
    aqA[0] = *(const short8*)qp;
    aqA[1] = *(const short8*)(qp + 32);
  }
  {
    const unsigned short* qp =
        Q + headoff + (size_t)(qB0 + slice * 16 + ml) * D_ + g * 8;
    aqB[0] = *(const short8*)qp;
    aqB[1] = *(const short8*)(qp + 32);
  }

  floatx4 accA[4], accB[4];
#pragma unroll
  for (int jd = 0; jd < 4; ++jd) {
    accA[jd] = (floatx4){0.f, 0.f, 0.f, 0.f};
    accB[jd] = (floatx4){0.f, 0.f, 0.f, 0.f};
  }
  float lA = 0.f, lB = 0.f;
  const int qgA = qA0 + slice * 16 + ml;   // this lane's q-row (A block)
  const int qgB = qB0 + slice * 16 + ml;

  // staging: waves 0-3 handle K, waves 4-7 handle V; each covers 16 rows.
  const int sw = slice;
  const unsigned short* kgb =
      Kg + headoff + (size_t)(sw * 16 + (lane >> 2)) * D_ + (lane & 3) * 8;
  const unsigned short* vgb =
      Vt + vtoff + (size_t)(sw * 16 + (lane >> 2)) * S_ + (lane & 3) * 8;
  const int woff = sw * 512;

  const int ntiles = qbB + 1;

  // ---- stage group 0 into buf 0 (prologue; one unhidden drain) ----
  {
    const int cnt = (ntiles < KTPB) ? ntiles : KTPB;
#pragma unroll
    for (int t = 0; t < KTPB; ++t) {
      if (t >= cnt) break;
      if (w < 4) {
        const size_t ko = (size_t)t * 64 * D_;
        gll16(kgb + ko,      lds.t.k0[0][t] + woff);
        gll16(kgb + ko + 32, lds.t.k1[0][t] + woff);
      } else {
        gll16(vgb + t * 64,      lds.t.v0[0][t] + woff);
        gll16(vgb + t * 64 + 32, lds.t.v1[0][t] + woff);
      }
    }
  }
  __syncthreads();

  for (int kt0 = 0; kt0 < ntiles; kt0 += KTPB) {
    const int bufi = (kt0 >> 1) & 1;
    // ---- stage NEXT group into buf^1 (issue early; drained at barrier) ----
    const int nxt = kt0 + KTPB;
    if (nxt < ntiles) {
      const int cn = (ntiles - nxt < KTPB) ? (ntiles - nxt) : KTPB;
#pragma unroll
      for (int t = 0; t < KTPB; ++t) {
        if (t >= cn) break;
        const int kt = nxt + t;
        if (w < 4) {
          const size_t ko = (size_t)kt * 64 * D_;
          gll16(kgb + ko,      lds.t.k0[bufi ^ 1][t] + woff);
          gll16(kgb + ko + 32, lds.t.k1[bufi ^ 1][t] + woff);
        } else {
          gll16(vgb + kt * 64,      lds.t.v0[bufi ^ 1][t] + woff);
          gll16(vgb + kt * 64 + 32, lds.t.v1[bufi ^ 1][t] + woff);
        }
      }
    }

    // ---- compute current buf (A/B fused when both in causal range) ----
    const int cnt = (ntiles - kt0 < KTPB) ? (ntiles - kt0) : KTPB;  // uniform
    if (par < cnt) {
      const int kt = kt0 + par;
      const int kb = kt * 64 + g * 4;
      if (kt <= qbA)
        attn_tile2<true>(aqB, aqA,
                         lds.t.k0[bufi][par], lds.t.k1[bufi][par],
                         lds.t.v0[bufi][par], lds.t.v1[bufi][par],
                         accB, lB, accA, lA,
                         kt == qbB, kt == qbA, qgB, qgA, kb, g, ml);
      else
        attn_tile2<false>(aqB, aqA,
                          lds.t.k0[bufi][par], lds.t.k1[bufi][par],
                          lds.t.v0[bufi][par], lds.t.v1[bufi][par],
                          accB, lB, accA, lA,
                          kt == qbB, false, qgB, qgA, kb, g, ml);
    }
    __syncthreads();  // drains next-group loads (hidden under compute)
  }

  // ---- combine parity pairs (w, w+4) through LDS ----
  {
    float* slot = lds.comb + (size_t)(slice * 64 + lane) * 36;
    if (par == 1) {
#pragma unroll
      for (int jd = 0; jd < 4; ++jd) {
        *(floatx4*)(slot + jd * 4) = accA[jd];
        *(floatx4*)(slot + 16 + jd * 4) = accB[jd];
      }
      slot[32] = lA;
      slot[33] = lB;
    }
    __syncthreads();
    if (par == 1) return;  // upper waves done; no further barriers below
#pragma unroll
    for (int jd = 0; jd < 4; ++jd) {
      accA[jd] += *(const floatx4*)(slot + jd * 4);
      accB[jd] += *(const floatx4*)(slot + 16 + jd * 4);
    }
    lA += slot[32];
    lB += slot[33];
  }

  // reduce l across the 4 lanes sharing ml (k was spread over g), invert,
  // then fetch per-output-row values (row = g*4+r lives at lane ml=g*4+r).
  lA += __shfl_xor(lA, 16); lA += __shfl_xor(lA, 32);
  lB += __shfl_xor(lB, 16); lB += __shfl_xor(lB, 32);
  const float liA = 1.0f / lA;
  const float liB = 1.0f / lB;
  float lrA[4], lrB[4];
#pragma unroll
  for (int r = 0; r < 4; ++r) {
    lrA[r] = __shfl(liA, g * 4 + r);
    lrB[r] = __shfl(liB, g * 4 + r);
  }

#pragma unroll
  for (int r = 0; r < 4; ++r) {
    const int rowA = qA0 + slice * 16 + g * 4 + r;
    const int rowB = qB0 + slice * 16 + g * 4 + r;
#pragma unroll
    for (int jd = 0; jd < 4; ++jd) {
      CTX[headoff + (size_t)rowA * D_ + jd * 16 + ml] = f2bf(accA[jd][r] * lrA[r]);
      CTX[headoff + (size_t)rowB * D_ + jd * 16 + ml] = f2bf(accB[jd][r] * lrB[r]);
    }
  }
}

// ---------------------------------------------------------------------------
extern "C" void kernel_launch(void* const* d_in, const int* in_sizes, int n_in,
                              void* d_out, int out_size, void* d_ws, size_t ws_size,
                              hipStream_t stream)
{
  const float* X  = (const float*)d_in[0];
  const float* Wq = (const float*)d_in[1];
  const float* Wk = (const float*)d_in[2];
  const float* Wv = (const float*)d_in[3];
  const float* Wo = (const float*)d_in[4];
  const float* bo = (const float*)d_in[5];

  char* ws = (char*)d_ws;
  const size_t MB = 1024 * 1024;

  unsigned short* Qb  = (unsigned short*)(ws);            // 8 MB (CTX aliases)
  unsigned short* Kb  = (unsigned short*)(ws + 8 * MB);   // 8 MB
  unsigned short* Xb  = (unsigned short*)(ws + 16 * MB);  // 8 MB
  unsigned short* WT  = (unsigned short*)(ws + 24 * MB);  // WqT|WkT|WvT|WoT
  unsigned short* WoT = WT + (size_t)3 * 1024 * 1024;
  unsigned short* Vt  = (unsigned short*)d_out;           // low 8MB of d_out
                                                          // (dead after attn;
                                                          //  wo64 overwrites)

  // merged X-convert (z=4) + 4x W transpose/convert (z=0..3)
  prep_inputs<<<dim3(32, 32, 5), dim3(32, 8), 0, stream>>>(
      X, Xb, Wq, Wk, Wv, Wo, WT);
  // fused Q/K/V projection (512-thread 8-wave, 2D XCD chunk); V -> Vt direct
  gemm256_qkv<<<dim3(24, 32), 512, 0, stream>>>(Xb, WT, Qb, Kb, Vt);
  // fused A/B, 2-phase pipelined, XCD-swizzled attention; CTX aliases Q
  attn_v16<<<dim3(512), 512, 0, stream>>>(Qb, Kb, Vt, Qb);
  // output projection + bias (8-wave 64x128, BK=64, 512 blocks, XCD-swz)
  gemm_wo64<<<dim3(8, 64), 512, 0, stream>>>(Qb, WoT, bo, (float*)d_out);
}

// Round 16
// 175.818 us; speedup vs baseline: 1.1078x; 1.0075x over previous
//
#include <hip/hip_runtime.h>

// MultiHeadAttention: B=2, S=2048, D=1024, H=16, hd=64. fp32 I/O.
// Round 32: attn LOAD-BALANCED FLAT TILE LIST. Old: block iterates
// kt=0..qbB (17..32 iterations, p-dependent) -- every block does exactly
// 33 tile-computes but sparse (low-p) blocks pay ~2x the barrier/staging
// phases; with 2 blocks/CU the stragglers set kernel time. New: flatten
// to 33 tiles (fl<=qbB -> B-tile kt=fl; else A-tile kt=fl-qbB-1); each
// iteration computes flats {2j+par} -> EXACTLY 17 iterations for all
// blocks. Staging slots carry per-slot kt (overlap kts staged twice;
// FETCH +35% at 5% HBM = free). Dual-fusion dropped (worth 1.2us, R21);
// only attn_tile2<false> instantiation used (fewer templates, R27 lesson).
// qkv (R30 8-wave), wo64 (R31 8-wave), prep unchanged.

typedef __attribute__((ext_vector_type(8))) short short8;
typedef __attribute__((ext_vector_type(4))) short short4v;
typedef __attribute__((ext_vector_type(4))) float floatx4;

__device__ inline unsigned short f2bf(float f) {
  unsigned u = __float_as_uint(f);
  unsigned r = (u + 0x7fffu + ((u >> 16) & 1u)) >> 16;  // RNE
  return (unsigned short)r;
}

__device__ __forceinline__ float fast_exp2(float x) {
#if __has_builtin(__builtin_amdgcn_exp2f)
  return __builtin_amdgcn_exp2f(x);
#else
  float r;
  asm volatile("v_exp_f32_e32 %0, %1" : "=v"(r) : "v"(x));
  return r;
#endif
}

__device__ __forceinline__ void gll16(const unsigned short* g, unsigned short* l) {
  __builtin_amdgcn_global_load_lds(
      (const __attribute__((address_space(1))) unsigned int*)(g),
      (__attribute__((address_space(3))) unsigned int*)(l),
      16, 0, 0);
}

constexpr int B_ = 2, S_ = 2048, D_ = 1024, H_ = 16, HD_ = 64;

// ---------------------------------------------------------------------------
// Merged one-time converter: z=0..3 -> W transpose+convert; z=4 -> X convert.
// ---------------------------------------------------------------------------
__global__ __launch_bounds__(256) void prep_inputs(
    const float* __restrict__ x, unsigned short* __restrict__ xb,
    const float* __restrict__ w0, const float* __restrict__ w1,
    const float* __restrict__ w2, const float* __restrict__ w3,
    unsigned short* __restrict__ wt_base)
{
  if (blockIdx.z == 4) {
    const int tid = threadIdx.y * 32 + threadIdx.x;
    const size_t base =
        ((size_t)(blockIdx.y * 32 + blockIdx.x) * 256 + tid) * 16;
#pragma unroll
    for (int half = 0; half < 2; ++half) {
      const size_t i = base + half * 8;
      float4 a = *(const float4*)(x + i);
      float4 b = *(const float4*)(x + i + 4);
      short8 o;
      o[0] = (short)f2bf(a.x); o[1] = (short)f2bf(a.y);
      o[2] = (short)f2bf(a.z); o[3] = (short)f2bf(a.w);
      o[4] = (short)f2bf(b.x); o[5] = (short)f2bf(b.y);
      o[6] = (short)f2bf(b.z); o[7] = (short)f2bf(b.w);
      *(short8*)(xb + i) = o;
    }
    return;
  }
  const float* src;
  switch (blockIdx.z) {
    case 0: src = w0; break;
    case 1: src = w1; break;
    case 2: src = w2; break;
    default: src = w3; break;
  }
  unsigned short* dst = wt_base + (size_t)blockIdx.z * 1024 * 1024;
  __shared__ unsigned short t[32][33];
  const int bx = blockIdx.x * 32;  // n
  const int by = blockIdx.y * 32;  // k
  const int x_ = threadIdx.x;
  for (int yy = threadIdx.y; yy < 32; yy += 8)
    t[yy][x_] = f2bf(src[(size_t)(by + yy) * 1024 + bx + x_]);
  __syncthreads();
  for (int yy = threadIdx.y; yy < 32; yy += 8)
    dst[(size_t)(bx + yy) * 1024 + by + x_] = t[x_][yy];
}

// ---------------------------------------------------------------------------
// QKV GEMM (R30-exact): 128x128 tile, 512 threads / 8 waves (4m x 2n),
// BK=64 two-subtile staging, 2D XCD chunk. V written transposed into Vt.
// ---------------------------------------------------------------------------
__global__ __launch_bounds__(512) void gemm256_qkv(
    const unsigned short* __restrict__ A,
    const unsigned short* __restrict__ Bt,
    unsigned short* __restrict__ Qo,
    unsigned short* __restrict__ Ko,
    unsigned short* __restrict__ Vt)
{
  __shared__ unsigned short sA[2][128 * 32];
  __shared__ unsigned short sB[2][128 * 32];
  const int K = 1024;

  // 2D XCD chunk (bijective): xcd = L&7 owns rows [(xcd>>1)*8,+8) x
  // cols [(xcd&1)*12,+12), walked row-major: 12 B-panels (3MB) resident.
  const int L = blockIdx.y * 24 + blockIdx.x;
  const int xcd = L & 7, i = L >> 3;
  const int brow = (xcd >> 1) * 8 + i / 12;
  const int bcol = (xcd & 1) * 12 + i % 12;
  const int m0 = brow * 128;
  const int bn0 = bcol * 128;

  const int tid = threadIdx.x, wave = tid >> 6, lane = tid & 63;
  const int g = lane >> 4, ml = lane & 15;
  const int wm = wave & 3, wn = wave >> 2;  // 4 m-slices x 2 n-slices

  // staging: thread t covers row tid>>2 (0..127), chunk tid&3.
  const unsigned short* ag = A + (size_t)(m0 + (tid >> 2)) * K + (tid & 3) * 8;
  const unsigned short* bg = Bt + (size_t)(bn0 + (tid >> 2)) * K + (tid & 3) * 8;
  const int woff = wave * 512;  // lane*8 added by HW (wave-uniform base)

  floatx4 acc[2][4];
#pragma unroll
  for (int mt = 0; mt < 2; ++mt)
#pragma unroll
    for (int nt = 0; nt < 4; ++nt) acc[mt][nt] = (floatx4){0.f, 0.f, 0.f, 0.f};

  for (int k0 = 0; k0 < K; k0 += 64) {
    __syncthreads();
#pragma unroll
    for (int t = 0; t < 2; ++t) {
      gll16(ag + k0 + t * 32, sA[t] + woff);
      gll16(bg + k0 + t * 32, sB[t] + woff);
    }
    __syncthreads();
#pragma unroll
    for (int t = 0; t < 2; ++t) {
      short8 af[2], bf[4];
#pragma unroll
      for (int mt = 0; mt < 2; ++mt)
        af[mt] = *(const short8*)(sA[t] + (wm * 32 + mt * 16 + ml) * 32 + g * 8);
#pragma unroll
      for (int nt = 0; nt < 4; ++nt)
        bf[nt] = *(const short8*)(sB[t] + (wn * 64 + nt * 16 + ml) * 32 + g * 8);
#pragma unroll
      for (int mt = 0; mt < 2; ++mt)
#pragma unroll
        for (int nt = 0; nt < 4; ++nt)
          acc[mt][nt] = __builtin_amdgcn_mfma_f32_16x16x32_bf16(
              af[mt], bf[nt], acc[mt][nt], 0, 0, 0);
    }
  }

  const int proj = bcol >> 3;
  const int col0 = (bcol & 7) * 128;
  if (proj < 2) {
    unsigned short* out = (proj == 0) ? Qo : Ko;
#pragma unroll
    for (int mt = 0; mt < 2; ++mt) {
#pragma unroll
      for (int nt = 0; nt < 4; ++nt) {
        const int col = col0 + wn * 64 + nt * 16 + ml;
#pragma unroll
        for (int r = 0; r < 4; ++r) {
          const int row = m0 + wm * 32 + mt * 16 + g * 4 + r;
          out[(size_t)row * 1024 + col] = f2bf(acc[mt][nt][r]);
        }
      }
    }
  } else {
    // V: write transposed: Vt[((b*16+h)*64+d)*2048 + s], 4 consecutive s
    // (r=0..3) packed into one 8B store. b constant per block (128 | 2048).
    const int bq = m0 >> 11;
    const int sbase = (m0 & 2047);
#pragma unroll
    for (int mt = 0; mt < 2; ++mt) {
      const int s0 = sbase + wm * 32 + mt * 16 + g * 4;
#pragma unroll
      for (int nt = 0; nt < 4; ++nt) {
        const int col = col0 + wn * 64 + nt * 16 + ml;  // V column 0..1023
        const int h = col >> 6, d = col & 63;
        short4v o;
        o[0] = (short)f2bf(acc[mt][nt][0]);
        o[1] = (short)f2bf(acc[mt][nt][1]);
        o[2] = (short)f2bf(acc[mt][nt][2]);
        o[3] = (short)f2bf(acc[mt][nt][3]);
        *(short4v*)(Vt + ((size_t)((bq * 16 + h) * 64 + d)) * 2048 + s0) = o;
      }
    }
  }
}

// ---------------------------------------------------------------------------
// Output projection (R31-exact): 64x128 tile, 512 threads / 8 waves,
// BK=64 two-subtile staging (24KB LDS), XCD swizzle.
// ---------------------------------------------------------------------------
__global__ __launch_bounds__(512) void gemm_wo64(
    const unsigned short* __restrict__ A,
    const unsigned short* __restrict__ Bt,
    const float* __restrict__ bias,
    float* __restrict__ C)
{
  __shared__ unsigned short sA[2][64 * 32];   // 4KB each
  __shared__ unsigned short sB[2][128 * 32];  // 8KB each -> 24KB total
  const int K = 1024;

  // XCD swizzle (bijective: 512 % 8 == 0): 8 row-panels x 8 cols per XCD.
  const int L = blockIdx.y * 8 + blockIdx.x;
  const int rid = (L & 7) * 64 + (L >> 3);
  const int m0 = (rid >> 3) * 64;
  const int bn0 = (rid & 7) * 128;

  const int tid = threadIdx.x, wave = tid >> 6, lane = tid & 63;
  const int g = lane >> 4, ml = lane & 15;
  const int wm = wave & 1, wn = wave >> 1;  // 2 m-slices x 4 n-slices

  // A staging: wave w -> subtile sa=w>>2, quarter qa=w&3.
  const int sa = wave >> 2, qa = wave & 3;
  const unsigned short* ag =
      A + (size_t)(m0 + qa * 16 + (lane >> 2)) * K + sa * 32 + (lane & 3) * 8;
  unsigned short* const adst = sA[sa] + qa * 512;
  // B staging: chunks c = 2*wave + h (h=0,1): subtile c>>3, eighth c&7.
  const int c0 = wave * 2, c1 = wave * 2 + 1;
  const unsigned short* bg0 =
      Bt + (size_t)(bn0 + (c0 & 7) * 16 + (lane >> 2)) * K + (c0 >> 3) * 32 + (lane & 3) * 8;
  const unsigned short* bg1 =
      Bt + (size_t)(bn0 + (c1 & 7) * 16 + (lane >> 2)) * K + (c1 >> 3) * 32 + (lane & 3) * 8;
  unsigned short* const bdst0 = sB[c0 >> 3] + (c0 & 7) * 512;
  unsigned short* const bdst1 = sB[c1 >> 3] + (c1 & 7) * 512;

  floatx4 acc[2][2];
#pragma unroll
  for (int mt = 0; mt < 2; ++mt)
#pragma unroll
    for (int nt = 0; nt < 2; ++nt) acc[mt][nt] = (floatx4){0.f, 0.f, 0.f, 0.f};

  for (int k0 = 0; k0 < K; k0 += 64) {
    __syncthreads();
    gll16(ag + k0, adst);
    gll16(bg0 + k0, bdst0);
    gll16(bg1 + k0, bdst1);
    __syncthreads();
#pragma unroll
    for (int t = 0; t < 2; ++t) {
      short8 af[2], bf[2];
#pragma unroll
      for (int mt = 0; mt < 2; ++mt)
        af[mt] = *(const short8*)(sA[t] + (wm * 32 + mt * 16 + ml) * 32 + g * 8);
#pragma unroll
      for (int nt = 0; nt < 2; ++nt)
        bf[nt] = *(const short8*)(sB[t] + (wn * 32 + nt * 16 + ml) * 32 + g * 8);
#pragma unroll
      for (int mt = 0; mt < 2; ++mt)
#pragma unroll
        for (int nt = 0; nt < 2; ++nt)
          acc[mt][nt] = __builtin_amdgcn_mfma_f32_16x16x32_bf16(
              af[mt], bf[nt], acc[mt][nt], 0, 0, 0);
    }
  }

#pragma unroll
  for (int mt = 0; mt < 2; ++mt) {
#pragma unroll
    for (int nt = 0; nt < 2; ++nt) {
      const int col = bn0 + wn * 32 + nt * 16 + ml;
      const float badd = bias[col];
#pragma unroll
      for (int r = 0; r < 4; ++r) {
        const int row = m0 + wm * 32 + mt * 16 + g * 4 + r;
        C[(size_t)row * 1024 + col] = acc[mt][nt][r] + badd;
      }
    }
  }
}

// ---------------------------------------------------------------------------
// Attention v19: flat 33-tile list, 17 iterations for EVERY block.
// Base machinery (softmax_pack, attn_tile2<false>, staging, comb) = v16.
// LDS: 2 bufs x 2 slots x (K 8KB + V 8KB) = 64KB; union comb 36KB.
// ---------------------------------------------------------------------------
constexpr int KTPB = 2;  // tile slots per buffer group

struct AttnLds {
  unsigned short k0[2][KTPB][64 * 32];
  unsigned short k1[2][KTPB][64 * 32];
  unsigned short v0[2][KTPB][64 * 32];
  unsigned short v1[2][KTPB][64 * 32];
};
union __align__(16) AttnLdsU {
  AttnLds t;
  float comb[4 * 64 * 36];  // 36 KB <= 64 KB; used after last barrier
};

// softmax + pack + permlane redistribute: s -> ap[2] (PV A-frags).
// l sums RAW f32 (4 partials); v_perm byte-select truncates P to bf16.
__device__ __forceinline__ void softmax_pack(
    const floatx4* s, const bool diag, const int qg, const int kb,
    float& l, short8* ap)
{
  const float C1 = 0.18033688f;    // 0.125 / ln2
  const float C2 = -34.6246810f;   // -24 / ln2

  unsigned wb[4][4];
  float lp0 = 0.f, lp1 = 0.f, lp2 = 0.f, lp3 = 0.f;
#pragma unroll
  for (int nb = 0; nb < 4; ++nb) {
#pragma unroll
    for (int r = 0; r < 4; ++r) {
      float wv = fast_exp2(fmaf(s[nb][r], C1, C2));
      if (diag && (kb + nb * 16 + r > qg)) wv = 0.f;
      wb[nb][r] = __float_as_uint(wv);
      if (nb == 0) lp0 += wv;
      else if (nb == 1) lp1 += wv;
      else if (nb == 2) lp2 += wv;
      else lp3 += wv;
    }
  }
  l += (lp0 + lp1) + (lp2 + lp3);

  // pack pairs along r (v_perm bytes 2,3 of each source = truncated bf16)
  unsigned pk[4][2];
#pragma unroll
  for (int nb = 0; nb < 4; ++nb) {
    pk[nb][0] = __builtin_amdgcn_perm(wb[nb][1], wb[nb][0], 0x07060302u);
    pk[nb][1] = __builtin_amdgcn_perm(wb[nb][3], wb[nb][2], 0x07060302u);
  }

  // redistribute to PV A-frag: 2x permlane32_swap + 2x permlane16_swap per rr
  unsigned Fr[2][4];
#pragma unroll
  for (int rr = 0; rr < 2; ++rr) {
    unsigned a0 = pk[0][rr], a1 = pk[1][rr];
    unsigned a2 = pk[2][rr], a3 = pk[3][rr];
    asm("v_permlane32_swap_b32 %0, %1" : "+v"(a0), "+v"(a1));
    asm("v_permlane32_swap_b32 %0, %1" : "+v"(a2), "+v"(a3));
    asm("v_permlane16_swap_b32 %0, %1" : "+v"(a0), "+v"(a1));
    asm("v_permlane16_swap_b32 %0, %1" : "+v"(a2), "+v"(a3));
    Fr[0][rr] = a0; Fr[0][2 + rr] = a1;
    Fr[1][rr] = a2; Fr[1][2 + rr] = a3;
  }
#pragma unroll
  for (int f = 0; f < 2; ++f) {
    union { unsigned u[4]; short8 s8; } uap;
    uap.u[0] = Fr[f][0]; uap.u[1] = Fr[f][1];
    uap.u[2] = Fr[f][2]; uap.u[3] = Fr[f][3];
    ap[f] = uap.s8;
  }
}

// Single-tile compute (DUAL=false path of v16, unchanged codegen).
template <bool DUAL>
__device__ __forceinline__ void attn_tile2(
    const short8* aqB, const short8* aqA,
    const unsigned short* sK0, const unsigned short* sK1,
    const unsigned short* sV0, const unsigned short* sV1,
    floatx4* accB, float& lB, floatx4* accA, float& lA,
    const bool diagB, const bool diagA,
    const int qgB, const int qgA, const int kb,
    const int g, const int ml)
{
  floatx4 sB[4], sA[4];
  __builtin_amdgcn_s_setprio(1);
#pragma unroll
  for (int nb = 0; nb < 4; ++nb) {
    short8 bk0 = *(const short8*)(sK0 + (nb * 16 + ml) * 32 + g * 8);
    short8 bk1 = *(const short8*)(sK1 + (nb * 16 + ml) * 32 + g * 8);
    sB[nb] = (floatx4){0.f, 0.f, 0.f, 0.f};
    sB[nb] = __builtin_amdgcn_mfma_f32_16x16x32_bf16(bk0, aqB[0], sB[nb], 0, 0, 0);
    sB[nb] = __builtin_amdgcn_mfma_f32_16x16x32_bf16(bk1, aqB[1], sB[nb], 0, 0, 0);
    if (DUAL) {
      sA[nb] = (floatx4){0.f, 0.f, 0.f, 0.f};
      sA[nb] = __builtin_amdgcn_mfma_f32_16x16x32_bf16(bk0, aqA[0], sA[nb], 0, 0, 0);
      sA[nb] = __builtin_amdgcn_mfma_f32_16x16x32_bf16(bk1, aqA[1], sA[nb], 0, 0, 0);
    }
  }
  __builtin_amdgcn_s_setprio(0);

  short8 apB[2], apA[2];
  softmax_pack(sB, diagB, qgB, kb, lB, apB);
  if (DUAL) softmax_pack(sA, diagA, qgA, kb, lA, apA);

  __builtin_amdgcn_s_setprio(1);
#pragma unroll
  for (int f = 0; f < 2; ++f) {
    const unsigned short* sv = f ? sV1 : sV0;
#pragma unroll
    for (int jd = 0; jd < 4; ++jd) {
      short8 bv = *(const short8*)(sv + (jd * 16 + ml) * 32 + g * 8);
      accB[jd] = __builtin_amdgcn_mfma_f32_16x16x32_bf16(apB[f], bv, accB[jd], 0, 0, 0);
      if (DUAL)
        accA[jd] = __builtin_amdgcn_mfma_f32_16x16x32_bf16(apA[f], bv, accA[jd], 0, 0, 0);
    }
  }
  __builtin_amdgcn_s_setprio(0);
}

__global__ __launch_bounds__(512) void attn_v19(
    const unsigned short* __restrict__ Q,
    const unsigned short* __restrict__ Kg,
    const unsigned short* __restrict__ Vt,
    unsigned short* __restrict__ CTX)
{
  __shared__ AttnLdsU lds;

  // XCD-chunked swizzle (bijective: 512 % 8 == 0): groups 4 consecutive bh
  // per XCD -> K/V working set 2MB < 4MB L2.
  const int L = blockIdx.x;
  const int rid = (L & 7) * 64 + (L >> 3);
  const int p = rid & 15;
  const int bh = rid >> 4;

  const int b = bh >> 4, h = bh & 15;
  const int qbA = p, qbB = 31 - p;
  const int qA0 = qbA * 64, qB0 = qbB * 64;
  const int tid = threadIdx.x, w = tid >> 6, lane = tid & 63;
  const int slice = w & 3, par = w >> 2;
  const int g = lane >> 4, ml = lane & 15;

  const size_t headoff = (size_t)b * S_ * D_ + (size_t)h * HD_;
  const size_t vtoff   = (size_t)bh * HD_ * S_;

  short8 aqA[2], aqB[2];
  {
    const unsigned short* qp =
        Q + headoff + (size_t)(qA0 + slice * 16 + ml) * D_ + g * 8;
    aqA[0] = *(const short8*)qp;
    aqA[1] = *(const short8*)(qp + 32);
  }
  {
    const unsigned short* qp =
        Q + headoff + (size_t)(qB0 + slice * 16 + ml) * D_ + g * 8;
    aqB[0] = *(const short8*)qp;
    aqB[1] = *(const short8*)(qp + 32);
  }

  floatx4 accA[4], accB[4];
#pragma unroll
  for (int jd = 0; jd < 4; ++jd) {
    accA[jd] = (floatx4){0.f, 0.f, 0.f, 0.f};
    accB[jd] = (floatx4){0.f, 0.f, 0.f, 0.f};
  }
  float lA = 0.f, lB = 0.f;
  const int qgA = qA0 + slice * 16 + ml;   // this lane's q-row (A block)
  const int qgB = qB0 + slice * 16 + ml;

  // staging: waves 0-3 handle K, waves 4-7 handle V; each covers 16 rows.
  const int sw = slice;
  const unsigned short* kgb =
      Kg + headoff + (size_t)(sw * 16 + (lane >> 2)) * D_ + (lane & 3) * 8;
  const unsigned short* vgb =
      Vt + vtoff + (size_t)(sw * 16 + (lane >> 2)) * S_ + (lane & 3) * 8;
  const int woff = sw * 512;

  // flat tile list: fl <= qbB -> (B, kt=fl); else (A, kt=fl-qbB-1). 33 flats.
  const int qbBp1 = qbB + 1;
  const int NFLAT = 33;   // qbA+1 + qbB+1, constant for all blocks

  // ---- prologue: stage flats 0,1 (both B, kt=0,1 since qbB>=16) ----
#pragma unroll
  for (int t = 0; t < KTPB; ++t) {
    if (w < 4) {
      const size_t ko = (size_t)t * 64 * D_;
      gll16(kgb + ko,      lds.t.k0[0][t] + woff);
      gll16(kgb + ko + 32, lds.t.k1[0][t] + woff);
    } else {
      gll16(vgb + t * 64,      lds.t.v0[0][t] + woff);
      gll16(vgb + t * 64 + 32, lds.t.v1[0][t] + woff);
    }
  }
  __syncthreads();

  for (int j = 0; j < 17; ++j) {
    const int bufi = j & 1;
    // ---- stage next group's flats 2j+2, 2j+3 into buf^1 ----
#pragma unroll
    for (int t = 0; t < KTPB; ++t) {
      const int fl = 2 * (j + 1) + t;
      if (fl < NFLAT) {
        const int kt = (fl < qbBp1) ? fl : (fl - qbBp1);
        if (w < 4) {
          const size_t ko = (size_t)kt * 64 * D_;
          gll16(kgb + ko,      lds.t.k0[bufi ^ 1][t] + woff);
          gll16(kgb + ko + 32, lds.t.k1[bufi ^ 1][t] + woff);
        } else {
          gll16(vgb + kt * 64,      lds.t.v0[bufi ^ 1][t] + woff);
          gll16(vgb + kt * 64 + 32, lds.t.v1[bufi ^ 1][t] + woff);
        }
      }
    }

    // ---- compute this wave's flat tile (wave-uniform branch) ----
    const int fl = 2 * j + par;
    if (fl < NFLAT) {
      const bool isB = fl < qbBp1;
      const int kt = isB ? fl : (fl - qbBp1);
      const int kb = kt * 64 + g * 4;
      const unsigned short* k0p = lds.t.k0[bufi][par];
      const unsigned short* k1p = lds.t.k1[bufi][par];
      const unsigned short* v0p = lds.t.v0[bufi][par];
      const unsigned short* v1p = lds.t.v1[bufi][par];
      if (isB)
        attn_tile2<false>(aqB, aqA, k0p, k1p, v0p, v1p,
                          accB, lB, accA, lA,
                          fl == qbB, false, qgB, qgA, kb, g, ml);
      else
        attn_tile2<false>(aqA, aqB, k0p, k1p, v0p, v1p,
                          accA, lA, accB, lB,
                          fl == NFLAT - 1, false, qgA, qgB, kb, g, ml);
    }
    __syncthreads();  // drains next-group loads (hidden under compute)
  }

  // ---- combine parity pairs (w, w+4) through LDS ----
  {
    float* slot = lds.comb + (size_t)(slice * 64 + lane) * 36;
    if (par == 1) {
#pragma unroll
      for (int jd = 0; jd < 4; ++jd) {
        *(floatx4*)(slot + jd * 4) = accA[jd];
        *(floatx4*)(slot + 16 + jd * 4) = accB[jd];
      }
      slot[32] = lA;
      slot[33] = lB;
    }
    __syncthreads();
    if (par == 1) return;  // upper waves done; no further barriers below
#pragma unroll
    for (int jd = 0; jd < 4; ++jd) {
      accA[jd] += *(const floatx4*)(slot + jd * 4);
      accB[jd] += *(const floatx4*)(slot + 16 + jd * 4);
    }
    lA += slot[32];
    lB += slot[33];
  }

  // reduce l across the 4 lanes sharing ml (k was spread over g), invert,
  // then fetch per-output-row values (row = g*4+r lives at lane ml=g*4+r).
  lA += __shfl_xor(lA, 16); lA += __shfl_xor(lA, 32);
  lB += __shfl_xor(lB, 16); lB += __shfl_xor(lB, 32);
  const float liA = 1.0f / lA;
  const float liB = 1.0f / lB;
  float lrA[4], lrB[4];
#pragma unroll
  for (int r = 0; r < 4; ++r) {
    lrA[r] = __shfl(liA, g * 4 + r);
    lrB[r] = __shfl(liB, g * 4 + r);
  }

#pragma unroll
  for (int r = 0; r < 4; ++r) {
    const int rowA = qA0 + slice * 16 + g * 4 + r;
    const int rowB = qB0 + slice * 16 + g * 4 + r;
#pragma unroll
    for (int jd = 0; jd < 4; ++jd) {
      CTX[headoff + (size_t)rowA * D_ + jd * 16 + ml] = f2bf(accA[jd][r] * lrA[r]);
      CTX[headoff + (size_t)rowB * D_ + jd * 16 + ml] = f2bf(accB[jd][r] * lrB[r]);
    }
  }
}

// ---------------------------------------------------------------------------
extern "C" void kernel_launch(void* const* d_in, const int* in_sizes, int n_in,
                              void* d_out, int out_size, void* d_ws, size_t ws_size,
                              hipStream_t stream)
{
  const float* X  = (const float*)d_in[0];
  const float* Wq = (const float*)d_in[1];
  const float* Wk = (const float*)d_in[2];
  const float* Wv = (const float*)d_in[3];
  const float* Wo = (const float*)d_in[4];
  const float* bo = (const float*)d_in[5];

  char* ws = (char*)d_ws;
  const size_t MB = 1024 * 1024;

  unsigned short* Qb  = (unsigned short*)(ws);            // 8 MB (CTX aliases)
  unsigned short* Kb  = (unsigned short*)(ws + 8 * MB);   // 8 MB
  unsigned short* Xb  = (unsigned short*)(ws + 16 * MB);  // 8 MB
  unsigned short* WT  = (unsigned short*)(ws + 24 * MB);  // WqT|WkT|WvT|WoT
  unsigned short* WoT = WT + (size_t)3 * 1024 * 1024;
  unsigned short* Vt  = (unsigned short*)d_out;           // low 8MB of d_out
                                                          // (dead after attn;
                                                          //  wo64 overwrites)

  // merged X-convert (z=4) + 4x W transpose/convert (z=0..3)
  prep_inputs<<<dim3(32, 32, 5), dim3(32, 8), 0, stream>>>(
      X, Xb, Wq, Wk, Wv, Wo, WT);
  // fused Q/K/V projection (512-thread 8-wave, 2D XCD chunk); V -> Vt direct
  gemm256_qkv<<<dim3(24, 32), 512, 0, stream>>>(Xb, WT, Qb, Kb, Vt);
  // load-balanced flat-tile attention (17 iterations/block); CTX aliases Q
  attn_v19<<<dim3(512), 512, 0, stream>>>(Qb, Kb, Vt, Qb);
  // output projection + bias (8-wave 64x128, BK=64, 512 blocks, XCD-swz)
  gemm_wo64<<<dim3(8, 64), 512, 0, stream>>>(Qb, WoT, bo, (float*)d_out);
}